// Round 18
// baseline (1066.810 us; speedup 1.0000x reference)
//
#include <hip/hip_runtime.h>

typedef unsigned short u16;
typedef __attribute__((ext_vector_type(8))) __bf16 bf16x8;
typedef __attribute__((ext_vector_type(4))) float floatx4;

#define B_ 2
#define L_ 512
#define D_ 1024
#define N_ 16
#define R_ 64
#define DEPTH_ 4
#define V_ 50000
#define MLP_ 4096
#define MROWS (B_ * L_)
#define SCAN_C 32
#define SCAN_S (L_ / SCAN_C)  // 16

// LDS XOR swizzle for 128-byte rows (BK=64 bf16). Involution: SWZ(SWZ(b)) == b.
#define SWZ(b) ((b) ^ ((((b) >> 7) & 7) << 4))

// ---------- helpers ----------
__device__ __forceinline__ float b2f(u16 u) {
    unsigned int i = ((unsigned int)u) << 16;
    return __builtin_bit_cast(float, i);
}
__device__ __forceinline__ u16 f2b(float f) {
    return __builtin_bit_cast(u16, (__bf16)f);
}
__device__ __forceinline__ uint2 f4_to_b4(float4 v) {
    u16 a = f2b(v.x), b = f2b(v.y), c = f2b(v.z), d = f2b(v.w);
    uint2 r;
    r.x = (unsigned int)a | ((unsigned int)b << 16);
    r.y = (unsigned int)c | ((unsigned int)d << 16);
    return r;
}
__device__ __forceinline__ void async16(const void* g, void* l) {
    __builtin_amdgcn_global_load_lds(
        (const __attribute__((address_space(1))) void*)g,
        (__attribute__((address_space(3))) void*)l, 16, 0, 0);
}
template <int Ncnt>
__device__ __forceinline__ void waitcnt_vm() {
    if constexpr (Ncnt == 0) asm volatile("s_waitcnt vmcnt(0)" ::: "memory");
    else if constexpr (Ncnt == 2) asm volatile("s_waitcnt vmcnt(2)" ::: "memory");
    else if constexpr (Ncnt == 3) asm volatile("s_waitcnt vmcnt(3)" ::: "memory");
    else if constexpr (Ncnt == 4) asm volatile("s_waitcnt vmcnt(4)" ::: "memory");
    else if constexpr (Ncnt == 6) asm volatile("s_waitcnt vmcnt(6)" ::: "memory");
    else if constexpr (Ncnt == 8) asm volatile("s_waitcnt vmcnt(8)" ::: "memory");
    else if constexpr (Ncnt == 12) asm volatile("s_waitcnt vmcnt(12)" ::: "memory");
    else if constexpr (Ncnt == 16) asm volatile("s_waitcnt vmcnt(16)" ::: "memory");
    else asm volatile("s_waitcnt vmcnt(0)" ::: "memory");
}
__device__ __forceinline__ float silu_f(float v) { return v / (1.f + expf(-v)); }
__device__ __forceinline__ float gelu_f(float v) {
    return 0.5f * v * (1.f + erff(v * 0.7071067811865476f));
}
__device__ __forceinline__ float softplus_f(float v) {
    return fmaxf(v, 0.f) + log1pf(expf(-fabsf(v)));
}

// ---------- f32 -> bf16 bulk convert ----------
__global__ __launch_bounds__(256) void cvt_kernel(const float* __restrict__ in,
                                                  u16* __restrict__ out, const int n8) {
    const int i = blockIdx.x * 256 + threadIdx.x;
    if (i >= n8) return;
    const float4 a = *reinterpret_cast<const float4*>(&in[(size_t)i * 8]);
    const float4 b = *reinterpret_cast<const float4*>(&in[(size_t)i * 8 + 4]);
    uint4 o;
    uint2 lo = f4_to_b4(a), hi = f4_to_b4(b);
    o.x = lo.x; o.y = lo.y; o.z = hi.x; o.w = hi.y;
    *reinterpret_cast<uint4*>(&out[(size_t)i * 8]) = o;
}

// ---------- MFMA GEMM: C[M,N] = act(A[M,K] @ W[N,K]^T + bias) ----------
// PD=2 && both-u16: 2-deep prefetch, 3 LDS buffers, counted vmcnt (layers).
// PD=0: single-buffered (DMA for u16, reg-cvt for f32) — head / mixed (r13 config).
template <int BM, int BN, int ACT, int RES, int PD, typename AT, typename WT, typename OUT>
__global__ __launch_bounds__(256) void gemm_bt(
    const AT* __restrict__ A, const int lda,
    const WT* __restrict__ W, const WT* __restrict__ W2,
    const float* __restrict__ bias,
    OUT* __restrict__ out, OUT* __restrict__ out2,
    const int N, const int K, const int nt) {
    constexpr int BK = 64;
    constexpr int MI = BM / 32;
    constexpr int NI = BN / 32;
    constexpr int WM = BM / 2;
    constexpr bool PIPE = (PD == 2) && (sizeof(AT) == 2) && (sizeof(WT) == 2);
    constexpr int NBUF = PIPE ? 3 : 1;
    __shared__ alignas(16) u16 lA[NBUF * BM * BK];
    __shared__ alignas(16) u16 lW[NBUF * BN * BK];
    const int tid = threadIdx.x;
    const int lane = tid & 63, wv = tid >> 6;
    const int bid = blockIdx.x;

    const int m0 = (bid / nt) * BM;
    int n0 = (bid % nt) * BN;
    const WT* Wp = W;
    OUT* op = out;
    if (W2 != nullptr && n0 >= N) {
        Wp = W2;
        op = out2;
        n0 -= N;
    }
    const int wr = wv >> 1, wc = wv & 1;
    const int lr = lane & 15, kg = lane >> 4;

    floatx4 acc[MI][NI];
#pragma unroll
    for (int i = 0; i < MI; ++i)
#pragma unroll
        for (int j = 0; j < NI; ++j) {
            floatx4 z4 = {0.f, 0.f, 0.f, 0.f};
            acc[i][j] = z4;
        }

    const int T = K / BK;

    if constexpr (PIPE) {
        constexpr int P = BM / 32 + BN / 32;  // per-thread DMAs per tile
        auto issue = [&](int t) {
            const int buf = t % 3;
            const int kt = t * BK;
#pragma unroll
            for (int c = wv; c < BM / 8; c += 4) {
                const int dst = c * 1024 + lane * 16;
                const int lg = SWZ(dst);
                const int row = lg >> 7, colb = lg & 127;
                async16((const char*)A + ((size_t)(m0 + row) * lda + kt) * 2 + colb,
                        (char*)lA + buf * BM * 128 + c * 1024);
            }
#pragma unroll
            for (int c = wv; c < BN / 8; c += 4) {
                const int dst = c * 1024 + lane * 16;
                const int lg = SWZ(dst);
                const int row = lg >> 7, colb = lg & 127;
                int rn = n0 + row;
                rn = (rn < N) ? rn : (N - 1);
                async16((const char*)Wp + ((size_t)rn * K + kt) * 2 + colb,
                        (char*)lW + buf * BN * 128 + c * 1024);
            }
        };
        issue(0);
        if (T > 1) issue(1);
        for (int t = 0; t < T; ++t) {
            if (t + 2 < T) {
                issue(t + 2);
                waitcnt_vm<2 * P>();
            } else if (t + 1 < T) {
                waitcnt_vm<P>();
            } else {
                waitcnt_vm<0>();
            }
            __builtin_amdgcn_s_barrier();
            __builtin_amdgcn_sched_barrier(0);
            const char* bA = (const char*)lA + (t % 3) * BM * 128;
            const char* bW = (const char*)lW + (t % 3) * BN * 128;
#pragma unroll
            for (int kk = 0; kk < 2; ++kk) {
                bf16x8 aF[MI], bF[NI];
#pragma unroll
                for (int mi = 0; mi < MI; ++mi)
                    aF[mi] = *reinterpret_cast<const bf16x8*>(
                        bA + SWZ((wr * WM + mi * 16 + lr) * 128 + kk * 64 + kg * 16));
#pragma unroll
                for (int ni = 0; ni < NI; ++ni)
                    bF[ni] = *reinterpret_cast<const bf16x8*>(
                        bW + SWZ((wc * (BN / 2) + ni * 16 + lr) * 128 + kk * 64 + kg * 16));
#pragma unroll
                for (int mi = 0; mi < MI; ++mi)
#pragma unroll
                    for (int ni = 0; ni < NI; ++ni)
                        acc[mi][ni] = __builtin_amdgcn_mfma_f32_16x16x32_bf16(
                            aF[mi], bF[ni], acc[mi][ni], 0, 0, 0);
            }
            __builtin_amdgcn_sched_barrier(0);
            if (t + 1 < T) __builtin_amdgcn_s_barrier();
        }
    } else {
        for (int t = 0; t < T; ++t) {
            const int kt = t * BK;
            if (t) __syncthreads();
            if constexpr (sizeof(AT) == 2) {
#pragma unroll
                for (int c = wv; c < BM / 8; c += 4) {
                    const int dst = c * 1024 + lane * 16;
                    const int lg = SWZ(dst);
                    const int row = lg >> 7, colb = lg & 127;
                    async16((const char*)A + ((size_t)(m0 + row) * lda + kt) * 2 + colb,
                            (char*)lA + c * 1024);
                }
            } else {
                constexpr int ACHF = (BM * BK) / 1024;
                float4 raF[ACHF];
#pragma unroll
                for (int i = 0; i < ACHF; ++i) {
                    const int idx = tid + i * 256;
                    const int row = idx >> 4, c4 = (idx & 15) * 4;
                    raF[i] = *reinterpret_cast<const float4*>(&A[(size_t)(m0 + row) * lda + kt + c4]);
                }
#pragma unroll
                for (int i = 0; i < ACHF; ++i) {
                    const int idx = tid + i * 256;
                    const int row = idx >> 4, c4 = (idx & 15) * 4;
                    *reinterpret_cast<uint2*>((char*)lA + SWZ(row * 128 + c4 * 2)) = f4_to_b4(raF[i]);
                }
            }
            if constexpr (sizeof(WT) == 2) {
#pragma unroll
                for (int c = wv; c < BN / 8; c += 4) {
                    const int dst = c * 1024 + lane * 16;
                    const int lg = SWZ(dst);
                    const int row = lg >> 7, colb = lg & 127;
                    int rn = n0 + row;
                    rn = (rn < N) ? rn : (N - 1);
                    async16((const char*)Wp + ((size_t)rn * K + kt) * 2 + colb,
                            (char*)lW + c * 1024);
                }
            } else {
                constexpr int WCHF = (BN * BK) / 1024;
                float4 rwF[WCHF];
#pragma unroll
                for (int i = 0; i < WCHF; ++i) {
                    const int idx = tid + i * 256;
                    const int row = idx >> 4, c4 = (idx & 15) * 4;
                    int rn = n0 + row;
                    rn = (rn < N) ? rn : (N - 1);
                    rwF[i] = *reinterpret_cast<const float4*>(&Wp[(size_t)rn * K + kt + c4]);
                }
#pragma unroll
                for (int i = 0; i < WCHF; ++i) {
                    const int idx = tid + i * 256;
                    const int row = idx >> 4, c4 = (idx & 15) * 4;
                    *reinterpret_cast<uint2*>((char*)lW + SWZ(row * 128 + c4 * 2)) = f4_to_b4(rwF[i]);
                }
            }
            __syncthreads();
#pragma unroll
            for (int kk = 0; kk < 2; ++kk) {
                bf16x8 aF[MI], bF[NI];
#pragma unroll
                for (int mi = 0; mi < MI; ++mi)
                    aF[mi] = *reinterpret_cast<const bf16x8*>(
                        (const char*)lA + SWZ((wr * WM + mi * 16 + lr) * 128 + kk * 64 + kg * 16));
#pragma unroll
                for (int ni = 0; ni < NI; ++ni)
                    bF[ni] = *reinterpret_cast<const bf16x8*>(
                        (const char*)lW + SWZ((wc * (BN / 2) + ni * 16 + lr) * 128 + kk * 64 + kg * 16));
#pragma unroll
                for (int mi = 0; mi < MI; ++mi)
#pragma unroll
                    for (int ni = 0; ni < NI; ++ni)
                        acc[mi][ni] = __builtin_amdgcn_mfma_f32_16x16x32_bf16(
                            aF[mi], bF[ni], acc[mi][ni], 0, 0, 0);
            }
        }
    }

    // epilogue: D layout col = lane&15, row = (lane>>4)*4 + r; mi->r->ni order.
#pragma unroll
    for (int mi = 0; mi < MI; ++mi) {
        const int rb = m0 + wr * WM + mi * 16 + kg * 4;
#pragma unroll
        for (int r = 0; r < 4; ++r) {
            const size_t rowoff = (size_t)(rb + r) * (size_t)N;
#pragma unroll
            for (int ni = 0; ni < NI; ++ni) {
                const int col = n0 + wc * (BN / 2) + ni * 16 + lr;
                if (col >= N) continue;
                float v = acc[mi][ni][r] + (bias ? bias[col] : 0.f);
                if constexpr (ACT == 1) v = gelu_f(v);
                if constexpr (ACT == 2) v = softplus_f(v);
                const size_t o = rowoff + (size_t)col;
                if constexpr (RES) {
                    op[o] += v;
                } else if constexpr (sizeof(OUT) == 2) {
                    op[o] = f2b(v);
                } else {
                    op[o] = v;
                }
            }
        }
    }
}

// ---------- timestep embedding base ----------
__global__ __launch_bounds__(256) void temb0_kernel(const int* __restrict__ ts,
                                                    float* __restrict__ temb0) {
    int i = blockIdx.x * 256 + threadIdx.x;
    if (i >= B_ * D_) return;
    int b = i >> 10, k = i & 1023;
    float t = (float)ts[b];
    int h = (k < 512) ? k : (k - 512);
    float f = expf((float)h * (-9.210340371976184f / 511.f));
    float e = t * f;
    temb0[i] = (k < 512) ? sinf(e) : cosf(e);
}

// ---------- small row-dot GEMM (M=B) ----------
template <int ACTV>
__global__ __launch_bounds__(256) void rowdot_kernel(const float* __restrict__ in,
                                                     const float* __restrict__ W,
                                                     const float* __restrict__ bias,
                                                     float* __restrict__ out,
                                                     const int Ncols, const int K) {
    const int g = (blockIdx.x * 256 + threadIdx.x) >> 6;
    const int lane = threadIdx.x & 63;
    if (g >= B_ * Ncols) return;
    const int b = g / Ncols, j = g % Ncols;
    const float* xr = in + (size_t)b * K;
    const float* wr = W + (size_t)j * K;
    float s = 0.f;
    for (int k = lane; k < K; k += 64) s += xr[k] * wr[k];
#pragma unroll
    for (int o = 32; o; o >>= 1) s += __shfl_xor(s, o);
    if (lane == 0) {
        float v = s + bias[j];
        if (ACTV == 1) v = silu_f(v);
        out[(size_t)b * Ncols + j] = v;
    }
}

// ---------- embedding + temb broadcast ----------
__global__ __launch_bounds__(256) void embed_kernel(const int* __restrict__ ids,
                                                    const float* __restrict__ emb,
                                                    const float* __restrict__ temb2,
                                                    float* __restrict__ x) {
    const int gid = blockIdx.x * 256 + threadIdx.x;
    const int d8 = gid & 127;
    const int row = gid >> 7;
    const int b = row >> 9;
    const int d0 = d8 * 8;
    const int id = ids[row];
    const float4 e0 = *reinterpret_cast<const float4*>(&emb[(size_t)id * D_ + d0]);
    const float4 e1 = *reinterpret_cast<const float4*>(&emb[(size_t)id * D_ + d0 + 4]);
    const float4 t0 = *reinterpret_cast<const float4*>(&temb2[b * D_ + d0]);
    const float4 t1 = *reinterpret_cast<const float4*>(&temb2[b * D_ + d0 + 4]);
    float4 o0, o1;
    o0.x = e0.x + t0.x; o0.y = e0.y + t0.y; o0.z = e0.z + t0.z; o0.w = e0.w + t0.w;
    o1.x = e1.x + t1.x; o1.y = e1.y + t1.y; o1.z = e1.z + t1.z; o1.w = e1.w + t1.w;
    *reinterpret_cast<float4*>(&x[(size_t)row * D_ + d0]) = o0;
    *reinterpret_cast<float4*>(&x[(size_t)row * D_ + d0 + 4]) = o1;
}

// ---------- LayerNorm (f32 in, bf16 out) ----------
__global__ __launch_bounds__(256) void ln_kernel(const float* __restrict__ x,
                                                 const float* __restrict__ s,
                                                 const float* __restrict__ bb,
                                                 u16* __restrict__ out) {
    __shared__ float red[4];
    const int row = blockIdx.x, tid = threadIdx.x;
    const float4 v = *reinterpret_cast<const float4*>(x + (size_t)row * D_ + tid * 4);
    float sm = v.x + v.y + v.z + v.w;
#pragma unroll
    for (int o = 1; o < 64; o <<= 1) sm += __shfl_xor(sm, o);
    if ((tid & 63) == 0) red[tid >> 6] = sm;
    __syncthreads();
    const float mean = (red[0] + red[1] + red[2] + red[3]) * (1.f / 1024.f);
    __syncthreads();
    const float dx = v.x - mean, dy = v.y - mean, dz = v.z - mean, dw = v.w - mean;
    float sq = dx * dx + dy * dy + dz * dz + dw * dw;
#pragma unroll
    for (int o = 1; o < 64; o <<= 1) sq += __shfl_xor(sq, o);
    if ((tid & 63) == 0) red[tid >> 6] = sq;
    __syncthreads();
    const float var = (red[0] + red[1] + red[2] + red[3]) * (1.f / 1024.f);
    const float rs = rsqrtf(var + 1e-5f);
    const int c = tid * 4;
    const float4 sv = *reinterpret_cast<const float4*>(&s[c]);
    const float4 bv = *reinterpret_cast<const float4*>(&bb[c]);
    float4 o;
    o.x = dx * rs * sv.x + bv.x;
    o.y = dy * rs * sv.y + bv.y;
    o.z = dz * rs * sv.z + bv.z;
    o.w = dw * rs * sv.w + bv.w;
    *reinterpret_cast<uint2*>(&out[(size_t)row * D_ + c]) = f4_to_b4(o);
}

// ---------- chunked parallel selective scan, conv fused (sliding window) ----------
__global__ __launch_bounds__(256) void scan_p1(const u16* __restrict__ dt,
                                               const float* __restrict__ p,
                                               const u16* __restrict__ xr,
                                               const float* __restrict__ cw,
                                               const float* __restrict__ alog,
                                               float* __restrict__ Aprod,
                                               float* __restrict__ Hloc) {
    const int tid = threadIdx.x;
    const int ng = tid & 3;
    const int dl = tid >> 2;
    int blk = blockIdx.x;
    const int chunk = blk % SCAN_C; blk /= SCAN_C;
    const int dg = blk % (D_ / 64);
    const int b = blk / (D_ / 64);
    const int d = dg * 64 + dl;

    float a_v[4], inv_a[4];
#pragma unroll
    for (int j = 0; j < 4; ++j) {
        float av = -expf(alog[d * N_ + ng * 4 + j]);
        a_v[j] = av;
        inv_a[j] = 1.f / (av + 1e-10f);
    }
    const float4 cw4 = *reinterpret_cast<const float4*>(&cw[d * 4]);

    __shared__ float pbuf[SCAN_S * 32];
    const int t0 = chunk * SCAN_S;
    if (tid < SCAN_S * 8) {
        const int s = tid >> 3, off = (tid & 7) * 4;
        *reinterpret_cast<float4*>(&pbuf[s * 32 + off]) =
            *reinterpret_cast<const float4*>(&p[((size_t)(b * L_ + t0 + s)) * 96 + 64 + off]);
    }
    __syncthreads();

    const size_t base = (size_t)b * L_ * D_ + d;
    float xm3 = (t0 >= 3) ? b2f(xr[base + (size_t)(t0 - 3) * D_]) : 0.f;
    float xm2 = (t0 >= 2) ? b2f(xr[base + (size_t)(t0 - 2) * D_]) : 0.f;
    float xm1 = (t0 >= 1) ? b2f(xr[base + (size_t)(t0 - 1) * D_]) : 0.f;

    float A[4] = {1.f, 1.f, 1.f, 1.f};
    float h[4] = {0.f, 0.f, 0.f, 0.f};
#pragma unroll
    for (int s = 0; s < SCAN_S; ++s) {
        const size_t idx = base + (size_t)(t0 + s) * D_;
        const float xc = b2f(xr[idx]);
        const float uv = silu_f(cw4.x * xm3 + cw4.y * xm2 + cw4.z * xm1 + cw4.w * xc);
        xm3 = xm2; xm2 = xm1; xm1 = xc;
        const float dtv = b2f(dt[idx]);
#pragma unroll
        for (int j = 0; j < 4; ++j) {
            const float ex = fminf(dtv * a_v[j], 0.f);
            const float at = expf(ex);
            const float bt = (fabsf(a_v[j]) < 1e-8f) ? dtv : (at - 1.f) * inv_a[j];
            const float bp = pbuf[s * 32 + ng * 4 + j];
            A[j] *= at;
            h[j] = at * h[j] + bt * bp * uv;
        }
    }
    const size_t o = ((size_t)(b * SCAN_C + chunk) * D_ + d) * N_ + ng * 4;
    float4 a4 = {A[0], A[1], A[2], A[3]};
    float4 h4 = {h[0], h[1], h[2], h[3]};
    *reinterpret_cast<float4*>(&Aprod[o]) = a4;
    *reinterpret_cast<float4*>(&Hloc[o]) = h4;
}

__global__ __launch_bounds__(256) void scan_p2(const float* __restrict__ Aprod,
                                               const float* __restrict__ Hloc,
                                               float* __restrict__ Hstart) {
    const int gid = blockIdx.x * 256 + threadIdx.x;
    if (gid >= B_ * D_ * N_) return;
    const int b = gid / (D_ * N_);
    const int rem = gid % (D_ * N_);
    float H = 0.f;
#pragma unroll 8
    for (int k = 0; k < SCAN_C; ++k) {
        const size_t o = (size_t)(b * SCAN_C + k) * (D_ * N_) + rem;
        Hstart[o] = H;
        H = Aprod[o] * H + Hloc[o];
    }
}

__global__ __launch_bounds__(256) void scan_p3(const u16* __restrict__ dt,
                                               const float* __restrict__ p,
                                               const u16* __restrict__ xr,
                                               const float* __restrict__ cw,
                                               const u16* __restrict__ z,
                                               const float* __restrict__ alog,
                                               const float* __restrict__ Dp,
                                               const float* __restrict__ Hstart,
                                               u16* __restrict__ yg) {
    const int tid = threadIdx.x;
    const int ng = tid & 3;
    const int dl = tid >> 2;
    int blk = blockIdx.x;
    const int chunk = blk % SCAN_C; blk /= SCAN_C;
    const int dg = blk % (D_ / 64);
    const int b = blk / (D_ / 64);
    const int d = dg * 64 + dl;

    float a_v[4], inv_a[4];
#pragma unroll
    for (int j = 0; j < 4; ++j) {
        float av = -expf(alog[d * N_ + ng * 4 + j]);
        a_v[j] = av;
        inv_a[j] = 1.f / (av + 1e-10f);
    }
    const float Dpd = Dp[d];
    const float4 cw4 = *reinterpret_cast<const float4*>(&cw[d * 4]);

    __shared__ float pbuf[SCAN_S * 32];
    const int t0 = chunk * SCAN_S;
    if (tid < SCAN_S * 8) {
        const int s = tid >> 3, off = (tid & 7) * 4;
        *reinterpret_cast<float4*>(&pbuf[s * 32 + off]) =
            *reinterpret_cast<const float4*>(&p[((size_t)(b * L_ + t0 + s)) * 96 + 64 + off]);
    }
    __syncthreads();

    const size_t base = (size_t)b * L_ * D_ + d;
    float xm3 = (t0 >= 3) ? b2f(xr[base + (size_t)(t0 - 3) * D_]) : 0.f;
    float xm2 = (t0 >= 2) ? b2f(xr[base + (size_t)(t0 - 2) * D_]) : 0.f;
    float xm1 = (t0 >= 1) ? b2f(xr[base + (size_t)(t0 - 1) * D_]) : 0.f;

    float h[4];
    {
        const size_t o = ((size_t)(b * SCAN_C + chunk) * D_ + d) * N_ + ng * 4;
        const float4 h4 = *reinterpret_cast<const float4*>(&Hstart[o]);
        h[0] = h4.x; h[1] = h4.y; h[2] = h4.z; h[3] = h4.w;
    }

#pragma unroll
    for (int s = 0; s < SCAN_S; ++s) {
        const size_t idx = base + (size_t)(t0 + s) * D_;
        const float xc = b2f(xr[idx]);
        const float uv = silu_f(cw4.x * xm3 + cw4.y * xm2 + cw4.z * xm1 + cw4.w * xc);
        xm3 = xm2; xm2 = xm1; xm1 = xc;
        const float dtv = b2f(dt[idx]);
        float yp = 0.f;
#pragma unroll
        for (int j = 0; j < 4; ++j) {
            const float ex = fminf(dtv * a_v[j], 0.f);
            const float at = expf(ex);
            const float bt = (fabsf(a_v[j]) < 1e-8f) ? dtv : (at - 1.f) * inv_a[j];
            const float bp = pbuf[s * 32 + ng * 4 + j];
            const float cp = pbuf[s * 32 + 16 + ng * 4 + j];
            h[j] = at * h[j] + bt * bp * uv;
            yp += cp * h[j];
        }
        yp += __shfl_xor(yp, 1);
        yp += __shfl_xor(yp, 2);
        if (ng == 0) {
            const float zv = b2f(z[idx]);
            yg[idx] = f2b((yp + uv * Dpd) * silu_f(zv));
        }
    }
}

// ---------- launch ----------
extern "C" void kernel_launch(void* const* d_in, const int* in_sizes, int n_in,
                              void* d_out, int out_size, void* d_ws, size_t ws_size,
                              hipStream_t stream) {
    (void)in_sizes; (void)n_in; (void)out_size;
    const int* ids = (const int*)d_in[0];
    const int* tsteps = (const int*)d_in[1];
    const float* emb = (const float*)d_in[2];
    const float* tw1 = (const float*)d_in[3];
    const float* tb1 = (const float*)d_in[4];
    const float* tw2 = (const float*)d_in[5];
    const float* tb2 = (const float*)d_in[6];
    const float* ln1s = (const float*)d_in[7];
    const float* ln1b = (const float*)d_in[8];
    const float* wx = (const float*)d_in[9];
    const float* wz = (const float*)d_in[10];
    const float* wp = (const float*)d_in[11];
    const float* convw = (const float*)d_in[12];
    const float* dtw = (const float*)d_in[13];
    const float* dtb = (const float*)d_in[14];
    const float* alog = (const float*)d_in[15];
    const float* dp = (const float*)d_in[16];
    const float* wo = (const float*)d_in[17];
    const float* ln2s = (const float*)d_in[18];
    const float* ln2b = (const float*)d_in[19];
    const float* mw1 = (const float*)d_in[20];
    const float* mb1 = (const float*)d_in[21];
    const float* mw2 = (const float*)d_in[22];
    const float* mb2 = (const float*)d_in[23];
    const float* lnos = (const float*)d_in[24];
    const float* lnob = (const float*)d_in[25];
    const float* hw = (const float*)d_in[26];
    const float* hb = (const float*)d_in[27];
    float* outp = (float*)d_out;

    char* w = (char*)d_ws;
    size_t used = 0;
    auto alloc = [&](size_t bytes) {
        char* pp = w;
        size_t rb = (bytes + 255) & ~(size_t)255;
        w += rb;
        used += rb;
        return pp;
    };
    float* x = (float*)alloc((size_t)MROWS * D_ * 4);
    float* t0f = (float*)alloc((size_t)B_ * D_ * 4);
    float* t1f = (float*)alloc((size_t)B_ * MLP_ * 4);
    float* t2f = (float*)alloc((size_t)B_ * D_ * 4);
    u16* xnb = (u16*)alloc((size_t)MROWS * D_ * 2);
    u16* xres = (u16*)alloc((size_t)MROWS * D_ * 2);
    u16* zb = (u16*)alloc((size_t)MROWS * D_ * 2);
    float* pf = (float*)alloc((size_t)MROWS * 96 * 4);
    u16* dtb16 = (u16*)alloc((size_t)MROWS * D_ * 2);
    u16* ygb = (u16*)alloc((size_t)MROWS * D_ * 2);
    const bool cvt_head = (ws_size >= used + (size_t)V_ * D_ * 2 + 4096);
    u16* hwb = cvt_head ? (u16*)alloc((size_t)V_ * D_ * 2) : nullptr;
    const size_t lw_bytes = ((size_t)DEPTH_ * D_ * D_ * 3 + (size_t)DEPTH_ * 96 * D_ +
                             (size_t)DEPTH_ * D_ * R_ + (size_t)DEPTH_ * MLP_ * D_ * 2) * 2;
    const bool cvt_layer = cvt_head && (ws_size >= used + lw_bytes + ((size_t)1 << 20));
    u16 *wxb = nullptr, *wzb = nullptr, *wpb = nullptr, *dtwb = nullptr, *wob = nullptr,
        *mw1b = nullptr, *mw2b = nullptr;
    if (cvt_layer) {
        wxb = (u16*)alloc((size_t)DEPTH_ * D_ * D_ * 2);
        wzb = (u16*)alloc((size_t)DEPTH_ * D_ * D_ * 2);
        wpb = (u16*)alloc((size_t)DEPTH_ * 96 * D_ * 2);
        dtwb = (u16*)alloc((size_t)DEPTH_ * D_ * R_ * 2);
        wob = (u16*)alloc((size_t)DEPTH_ * D_ * D_ * 2);
        mw1b = (u16*)alloc((size_t)DEPTH_ * MLP_ * D_ * 2);
        mw2b = (u16*)alloc((size_t)DEPTH_ * MLP_ * D_ * 2);
    }
    u16* m1b = (u16*)outp;  // MLP hidden scratch in d_out (overwritten by head)
    float* Aprod = outp + (size_t)6 * 1024 * 1024;
    float* Hloc = outp + (size_t)8 * 1024 * 1024;
    float* Hstart = outp + (size_t)10 * 1024 * 1024;

    auto cvt = [&](const float* src, u16* dst, size_t n) {
        cvt_kernel<<<dim3((unsigned)((n / 8 + 255) / 256)), dim3(256), 0, stream>>>(src, dst,
                                                                                   (int)(n / 8));
    };
    if (cvt_head) cvt(hw, hwb, (size_t)V_ * D_);
    if (cvt_layer) {
        cvt(wx, wxb, (size_t)DEPTH_ * D_ * D_);
        cvt(wz, wzb, (size_t)DEPTH_ * D_ * D_);
        cvt(wp, wpb, (size_t)DEPTH_ * 96 * D_);
        cvt(dtw, dtwb, (size_t)DEPTH_ * D_ * R_);
        cvt(wo, wob, (size_t)DEPTH_ * D_ * D_);
        cvt(mw1, mw1b, (size_t)DEPTH_ * MLP_ * D_);
        cvt(mw2, mw2b, (size_t)DEPTH_ * MLP_ * D_);
    }
    temb0_kernel<<<dim3((B_ * D_ + 255) / 256), dim3(256), 0, stream>>>(tsteps, t0f);
    rowdot_kernel<1><<<dim3(B_ * MLP_ / 4), dim3(256), 0, stream>>>(t0f, tw1, tb1, t1f, MLP_, D_);
    rowdot_kernel<0><<<dim3(B_ * D_ / 4), dim3(256), 0, stream>>>(t1f, tw2, tb2, t2f, D_, MLP_);
    embed_kernel<<<dim3(MROWS * D_ / 8 / 256), dim3(256), 0, stream>>>(ids, emb, t2f, x);

    for (int i = 0; i < DEPTH_; ++i) {
        const float* cwi = convw + (size_t)i * D_ * 4;
        const float* dtbi = dtb + (size_t)i * D_;
        const float* ali = alog + (size_t)i * D_ * N_;
        const float* dpi = dp + (size_t)i * D_;
        const float* mb1i = mb1 + (size_t)i * MLP_;
        const float* mb2i = mb2 + (size_t)i * D_;

        ln_kernel<<<dim3(MROWS), dim3(256), 0, stream>>>(x, ln1s + i * D_, ln1b + i * D_, xnb);
        if (cvt_layer) {
            gemm_bt<32, 64, 0, 0, 2, u16, u16, u16><<<dim3(1024), dim3(256), 0, stream>>>(
                xnb, D_, wxb + (size_t)i * D_ * D_, wzb + (size_t)i * D_ * D_, nullptr,
                xres, zb, D_, D_, 32);
            gemm_bt<32, 64, 0, 0, 2, u16, u16, float><<<dim3(64), dim3(256), 0, stream>>>(
                xnb, D_, wpb + (size_t)i * 96 * D_, nullptr, nullptr, pf, nullptr, 96, D_, 2);
            gemm_bt<32, 64, 2, 0, 0, float, u16, u16><<<dim3(512), dim3(256), 0, stream>>>(
                pf, 96, dtwb + (size_t)i * D_ * R_, nullptr, dtbi, dtb16, nullptr, D_, R_, 16);
        } else {
            gemm_bt<32, 64, 0, 0, 0, u16, float, u16><<<dim3(1024), dim3(256), 0, stream>>>(
                xnb, D_, wx + (size_t)i * D_ * D_, wz + (size_t)i * D_ * D_, nullptr,
                xres, zb, D_, D_, 32);
            gemm_bt<32, 64, 0, 0, 0, u16, float, float><<<dim3(64), dim3(256), 0, stream>>>(
                xnb, D_, wp + (size_t)i * 96 * D_, nullptr, nullptr, pf, nullptr, 96, D_, 2);
            gemm_bt<32, 64, 2, 0, 0, float, float, u16><<<dim3(512), dim3(256), 0, stream>>>(
                pf, 96, dtw + (size_t)i * D_ * R_, nullptr, dtbi, dtb16, nullptr, D_, R_, 16);
        }
        scan_p1<<<dim3(B_ * (D_ / 64) * SCAN_C), dim3(256), 0, stream>>>(
            dtb16, pf, xres, cwi, ali, Aprod, Hloc);
        scan_p2<<<dim3(B_ * D_ * N_ / 256), dim3(256), 0, stream>>>(Aprod, Hloc, Hstart);
        scan_p3<<<dim3(B_ * (D_ / 64) * SCAN_C), dim3(256), 0, stream>>>(
            dtb16, pf, xres, cwi, zb, ali, dpi, Hstart, ygb);
        if (cvt_layer) {
            gemm_bt<32, 64, 0, 1, 2, u16, u16, float><<<dim3(512), dim3(256), 0, stream>>>(
                ygb, D_, wob + (size_t)i * D_ * D_, nullptr, nullptr, x, nullptr, D_, D_, 16);
        } else {
            gemm_bt<32, 64, 0, 1, 0, u16, float, float><<<dim3(512), dim3(256), 0, stream>>>(
                ygb, D_, wo + (size_t)i * D_ * D_, nullptr, nullptr, x, nullptr, D_, D_, 16);
        }
        ln_kernel<<<dim3(MROWS), dim3(256), 0, stream>>>(x, ln2s + i * D_, ln2b + i * D_, xnb);
        if (cvt_layer) {
            gemm_bt<32, 64, 1, 0, 2, u16, u16, u16><<<dim3(2048), dim3(256), 0, stream>>>(
                xnb, D_, mw1b + (size_t)i * MLP_ * D_, nullptr, mb1i, m1b, nullptr, MLP_, D_, 64);
            gemm_bt<32, 64, 0, 1, 2, u16, u16, float><<<dim3(512), dim3(256), 0, stream>>>(
                m1b, MLP_, mw2b + (size_t)i * MLP_ * D_, nullptr, mb2i, x, nullptr, D_, MLP_, 16);
        } else {
            gemm_bt<32, 64, 1, 0, 0, u16, float, u16><<<dim3(2048), dim3(256), 0, stream>>>(
                xnb, D_, mw1 + (size_t)i * MLP_ * D_, nullptr, mb1i, m1b, nullptr, MLP_, D_, 64);
            gemm_bt<32, 64, 0, 1, 0, u16, float, float><<<dim3(512), dim3(256), 0, stream>>>(
                m1b, MLP_, mw2 + (size_t)i * MLP_ * D_, nullptr, mb2i, x, nullptr, D_, MLP_, 16);
        }
    }

    ln_kernel<<<dim3(MROWS), dim3(256), 0, stream>>>(x, lnos, lnob, xnb);
    // head: exact r13 config (single-buffered DMA, BM=128/BN=128, n-major, no supertile)
    // — measured 185 us; supertile/pipeline variants were slower (latency-bound; r15-r17).
    constexpr int HNT = (V_ + 127) / 128;  // 391
    if (cvt_head) {
        gemm_bt<128, 128, 0, 0, 0, u16, u16, float>
            <<<dim3(8 * HNT), dim3(256), 0, stream>>>(
                xnb, D_, hwb, (const u16*)nullptr, hb, outp, nullptr, V_, D_, HNT);
    } else {
        gemm_bt<128, 128, 0, 0, 0, u16, float, float>
            <<<dim3(8 * HNT), dim3(256), 0, stream>>>(
                xnb, D_, hw, (const float*)nullptr, hb, outp, nullptr, V_, D_, HNT);
    }
}

// Round 19
// 1053.941 us; speedup vs baseline: 1.0122x; 1.0122x over previous
//
#include <hip/hip_runtime.h>

typedef unsigned short u16;
typedef __attribute__((ext_vector_type(8))) __bf16 bf16x8;
typedef __attribute__((ext_vector_type(4))) float floatx4;

#define B_ 2
#define L_ 512
#define D_ 1024
#define N_ 16
#define R_ 64
#define DEPTH_ 4
#define V_ 50000
#define MLP_ 4096
#define MROWS (B_ * L_)
#define SCAN_C 32
#define SCAN_S (L_ / SCAN_C)  // 16

// LDS XOR swizzle for 128-byte rows (BK=64 bf16). Involution: SWZ(SWZ(b)) == b.
#define SWZ(b) ((b) ^ ((((b) >> 7) & 7) << 4))

// ---------- helpers ----------
__device__ __forceinline__ float b2f(u16 u) {
    unsigned int i = ((unsigned int)u) << 16;
    return __builtin_bit_cast(float, i);
}
__device__ __forceinline__ u16 f2b(float f) {
    return __builtin_bit_cast(u16, (__bf16)f);
}
__device__ __forceinline__ uint2 f4_to_b4(float4 v) {
    u16 a = f2b(v.x), b = f2b(v.y), c = f2b(v.z), d = f2b(v.w);
    uint2 r;
    r.x = (unsigned int)a | ((unsigned int)b << 16);
    r.y = (unsigned int)c | ((unsigned int)d << 16);
    return r;
}
__device__ __forceinline__ void async16(const void* g, void* l) {
    __builtin_amdgcn_global_load_lds(
        (const __attribute__((address_space(1))) void*)g,
        (__attribute__((address_space(3))) void*)l, 16, 0, 0);
}
template <int Ncnt>
__device__ __forceinline__ void waitcnt_vm() {
    if constexpr (Ncnt == 0) asm volatile("s_waitcnt vmcnt(0)" ::: "memory");
    else if constexpr (Ncnt == 2) asm volatile("s_waitcnt vmcnt(2)" ::: "memory");
    else if constexpr (Ncnt == 3) asm volatile("s_waitcnt vmcnt(3)" ::: "memory");
    else if constexpr (Ncnt == 4) asm volatile("s_waitcnt vmcnt(4)" ::: "memory");
    else if constexpr (Ncnt == 6) asm volatile("s_waitcnt vmcnt(6)" ::: "memory");
    else if constexpr (Ncnt == 8) asm volatile("s_waitcnt vmcnt(8)" ::: "memory");
    else asm volatile("s_waitcnt vmcnt(0)" ::: "memory");
}
__device__ __forceinline__ float silu_f(float v) { return v / (1.f + expf(-v)); }
__device__ __forceinline__ float gelu_f(float v) {
    return 0.5f * v * (1.f + erff(v * 0.7071067811865476f));
}
__device__ __forceinline__ float softplus_f(float v) {
    return fmaxf(v, 0.f) + log1pf(expf(-fabsf(v)));
}

// ---------- f32 -> bf16 bulk convert ----------
__global__ __launch_bounds__(256) void cvt_kernel(const float* __restrict__ in,
                                                  u16* __restrict__ out, const int n8) {
    const int i = blockIdx.x * 256 + threadIdx.x;
    if (i >= n8) return;
    const float4 a = *reinterpret_cast<const float4*>(&in[(size_t)i * 8]);
    const float4 b = *reinterpret_cast<const float4*>(&in[(size_t)i * 8 + 4]);
    uint4 o;
    uint2 lo = f4_to_b4(a), hi = f4_to_b4(b);
    o.x = lo.x; o.y = lo.y; o.z = hi.x; o.w = hi.y;
    *reinterpret_cast<uint4*>(&out[(size_t)i * 8]) = o;
}

// ---------- MFMA GEMM: C[M,N] = act(A[M,K] @ W[N,K]^T + bias) ----------
// PD=1 && both-u16: 1-deep prefetch, 2 LDS buffers, counted vmcnt (layers; 24KB LDS,
//   6 blocks/CU — r18 showed 2-deep/3-buffer costs occupancy and loses ~150us).
// PD=0: single-buffered (DMA for u16, reg-cvt for f32) — head (r13 config) / mixed.
template <int BM, int BN, int ACT, int RES, int PD, typename AT, typename WT, typename OUT>
__global__ __launch_bounds__(256) void gemm_bt(
    const AT* __restrict__ A, const int lda,
    const WT* __restrict__ W, const WT* __restrict__ W2,
    const float* __restrict__ bias,
    OUT* __restrict__ out, OUT* __restrict__ out2,
    const int N, const int K, const int nt) {
    constexpr int BK = 64;
    constexpr int MI = BM / 32;
    constexpr int NI = BN / 32;
    constexpr int WM = BM / 2;
    constexpr bool PIPE = (PD == 1) && (sizeof(AT) == 2) && (sizeof(WT) == 2);
    constexpr int NBUF = PIPE ? 2 : 1;
    __shared__ alignas(16) u16 lA[NBUF * BM * BK];
    __shared__ alignas(16) u16 lW[NBUF * BN * BK];
    const int tid = threadIdx.x;
    const int lane = tid & 63, wv = tid >> 6;
    const int bid = blockIdx.x;

    const int m0 = (bid / nt) * BM;
    int n0 = (bid % nt) * BN;
    const WT* Wp = W;
    OUT* op = out;
    if (W2 != nullptr && n0 >= N) {
        Wp = W2;
        op = out2;
        n0 -= N;
    }
    const int wr = wv >> 1, wc = wv & 1;
    const int lr = lane & 15, kg = lane >> 4;

    floatx4 acc[MI][NI];
#pragma unroll
    for (int i = 0; i < MI; ++i)
#pragma unroll
        for (int j = 0; j < NI; ++j) {
            floatx4 z4 = {0.f, 0.f, 0.f, 0.f};
            acc[i][j] = z4;
        }

    const int T = K / BK;

    if constexpr (PIPE) {
        constexpr int P = BM / 32 + BN / 32;  // per-wave DMAs per tile
        auto issue = [&](int t) {
            const int buf = t & 1;
            const int kt = t * BK;
#pragma unroll
            for (int c = wv; c < BM / 8; c += 4) {
                const int dst = c * 1024 + lane * 16;
                const int lg = SWZ(dst);
                const int row = lg >> 7, colb = lg & 127;
                async16((const char*)A + ((size_t)(m0 + row) * lda + kt) * 2 + colb,
                        (char*)lA + buf * BM * 128 + c * 1024);
            }
#pragma unroll
            for (int c = wv; c < BN / 8; c += 4) {
                const int dst = c * 1024 + lane * 16;
                const int lg = SWZ(dst);
                const int row = lg >> 7, colb = lg & 127;
                int rn = n0 + row;
                rn = (rn < N) ? rn : (N - 1);
                async16((const char*)Wp + ((size_t)rn * K + kt) * 2 + colb,
                        (char*)lW + buf * BN * 128 + c * 1024);
            }
        };
        issue(0);
        for (int t = 0; t < T; ++t) {
            if (t + 1 < T) {
                issue(t + 1);
                waitcnt_vm<P>();
            } else {
                waitcnt_vm<0>();
            }
            __builtin_amdgcn_s_barrier();
            __builtin_amdgcn_sched_barrier(0);
            const char* bA = (const char*)lA + (t & 1) * BM * 128;
            const char* bW = (const char*)lW + (t & 1) * BN * 128;
#pragma unroll
            for (int kk = 0; kk < 2; ++kk) {
                bf16x8 aF[MI], bF[NI];
#pragma unroll
                for (int mi = 0; mi < MI; ++mi)
                    aF[mi] = *reinterpret_cast<const bf16x8*>(
                        bA + SWZ((wr * WM + mi * 16 + lr) * 128 + kk * 64 + kg * 16));
#pragma unroll
                for (int ni = 0; ni < NI; ++ni)
                    bF[ni] = *reinterpret_cast<const bf16x8*>(
                        bW + SWZ((wc * (BN / 2) + ni * 16 + lr) * 128 + kk * 64 + kg * 16));
#pragma unroll
                for (int mi = 0; mi < MI; ++mi)
#pragma unroll
                    for (int ni = 0; ni < NI; ++ni)
                        acc[mi][ni] = __builtin_amdgcn_mfma_f32_16x16x32_bf16(
                            aF[mi], bF[ni], acc[mi][ni], 0, 0, 0);
            }
            __builtin_amdgcn_sched_barrier(0);
            if (t + 1 < T) __builtin_amdgcn_s_barrier();
        }
    } else {
        for (int t = 0; t < T; ++t) {
            const int kt = t * BK;
            if (t) __syncthreads();
            if constexpr (sizeof(AT) == 2) {
#pragma unroll
                for (int c = wv; c < BM / 8; c += 4) {
                    const int dst = c * 1024 + lane * 16;
                    const int lg = SWZ(dst);
                    const int row = lg >> 7, colb = lg & 127;
                    async16((const char*)A + ((size_t)(m0 + row) * lda + kt) * 2 + colb,
                            (char*)lA + c * 1024);
                }
            } else {
                constexpr int ACHF = (BM * BK) / 1024;
                float4 raF[ACHF];
#pragma unroll
                for (int i = 0; i < ACHF; ++i) {
                    const int idx = tid + i * 256;
                    const int row = idx >> 4, c4 = (idx & 15) * 4;
                    raF[i] = *reinterpret_cast<const float4*>(&A[(size_t)(m0 + row) * lda + kt + c4]);
                }
#pragma unroll
                for (int i = 0; i < ACHF; ++i) {
                    const int idx = tid + i * 256;
                    const int row = idx >> 4, c4 = (idx & 15) * 4;
                    *reinterpret_cast<uint2*>((char*)lA + SWZ(row * 128 + c4 * 2)) = f4_to_b4(raF[i]);
                }
            }
            if constexpr (sizeof(WT) == 2) {
#pragma unroll
                for (int c = wv; c < BN / 8; c += 4) {
                    const int dst = c * 1024 + lane * 16;
                    const int lg = SWZ(dst);
                    const int row = lg >> 7, colb = lg & 127;
                    int rn = n0 + row;
                    rn = (rn < N) ? rn : (N - 1);
                    async16((const char*)Wp + ((size_t)rn * K + kt) * 2 + colb,
                            (char*)lW + c * 1024);
                }
            } else {
                constexpr int WCHF = (BN * BK) / 1024;
                float4 rwF[WCHF];
#pragma unroll
                for (int i = 0; i < WCHF; ++i) {
                    const int idx = tid + i * 256;
                    const int row = idx >> 4, c4 = (idx & 15) * 4;
                    int rn = n0 + row;
                    rn = (rn < N) ? rn : (N - 1);
                    rwF[i] = *reinterpret_cast<const float4*>(&Wp[(size_t)rn * K + kt + c4]);
                }
#pragma unroll
                for (int i = 0; i < WCHF; ++i) {
                    const int idx = tid + i * 256;
                    const int row = idx >> 4, c4 = (idx & 15) * 4;
                    *reinterpret_cast<uint2*>((char*)lW + SWZ(row * 128 + c4 * 2)) = f4_to_b4(rwF[i]);
                }
            }
            __syncthreads();
#pragma unroll
            for (int kk = 0; kk < 2; ++kk) {
                bf16x8 aF[MI], bF[NI];
#pragma unroll
                for (int mi = 0; mi < MI; ++mi)
                    aF[mi] = *reinterpret_cast<const bf16x8*>(
                        (const char*)lA + SWZ((wr * WM + mi * 16 + lr) * 128 + kk * 64 + kg * 16));
#pragma unroll
                for (int ni = 0; ni < NI; ++ni)
                    bF[ni] = *reinterpret_cast<const bf16x8*>(
                        (const char*)lW + SWZ((wc * (BN / 2) + ni * 16 + lr) * 128 + kk * 64 + kg * 16));
#pragma unroll
                for (int mi = 0; mi < MI; ++mi)
#pragma unroll
                    for (int ni = 0; ni < NI; ++ni)
                        acc[mi][ni] = __builtin_amdgcn_mfma_f32_16x16x32_bf16(
                            aF[mi], bF[ni], acc[mi][ni], 0, 0, 0);
            }
        }
    }

    // epilogue: D layout col = lane&15, row = (lane>>4)*4 + r; mi->r->ni order.
#pragma unroll
    for (int mi = 0; mi < MI; ++mi) {
        const int rb = m0 + wr * WM + mi * 16 + kg * 4;
#pragma unroll
        for (int r = 0; r < 4; ++r) {
            const size_t rowoff = (size_t)(rb + r) * (size_t)N;
#pragma unroll
            for (int ni = 0; ni < NI; ++ni) {
                const int col = n0 + wc * (BN / 2) + ni * 16 + lr;
                if (col >= N) continue;
                float v = acc[mi][ni][r] + (bias ? bias[col] : 0.f);
                if constexpr (ACT == 1) v = gelu_f(v);
                if constexpr (ACT == 2) v = softplus_f(v);
                const size_t o = rowoff + (size_t)col;
                if constexpr (RES) {
                    op[o] += v;
                } else if constexpr (sizeof(OUT) == 2) {
                    op[o] = f2b(v);
                } else {
                    op[o] = v;
                }
            }
        }
    }
}

// ---------- timestep embedding base ----------
__global__ __launch_bounds__(256) void temb0_kernel(const int* __restrict__ ts,
                                                    float* __restrict__ temb0) {
    int i = blockIdx.x * 256 + threadIdx.x;
    if (i >= B_ * D_) return;
    int b = i >> 10, k = i & 1023;
    float t = (float)ts[b];
    int h = (k < 512) ? k : (k - 512);
    float f = expf((float)h * (-9.210340371976184f / 511.f));
    float e = t * f;
    temb0[i] = (k < 512) ? sinf(e) : cosf(e);
}

// ---------- small row-dot GEMM (M=B) ----------
template <int ACTV>
__global__ __launch_bounds__(256) void rowdot_kernel(const float* __restrict__ in,
                                                     const float* __restrict__ W,
                                                     const float* __restrict__ bias,
                                                     float* __restrict__ out,
                                                     const int Ncols, const int K) {
    const int g = (blockIdx.x * 256 + threadIdx.x) >> 6;
    const int lane = threadIdx.x & 63;
    if (g >= B_ * Ncols) return;
    const int b = g / Ncols, j = g % Ncols;
    const float* xr = in + (size_t)b * K;
    const float* wr = W + (size_t)j * K;
    float s = 0.f;
    for (int k = lane; k < K; k += 64) s += xr[k] * wr[k];
#pragma unroll
    for (int o = 32; o; o >>= 1) s += __shfl_xor(s, o);
    if (lane == 0) {
        float v = s + bias[j];
        if (ACTV == 1) v = silu_f(v);
        out[(size_t)b * Ncols + j] = v;
    }
}

// ---------- embedding + temb broadcast ----------
__global__ __launch_bounds__(256) void embed_kernel(const int* __restrict__ ids,
                                                    const float* __restrict__ emb,
                                                    const float* __restrict__ temb2,
                                                    float* __restrict__ x) {
    const int gid = blockIdx.x * 256 + threadIdx.x;
    const int d8 = gid & 127;
    const int row = gid >> 7;
    const int b = row >> 9;
    const int d0 = d8 * 8;
    const int id = ids[row];
    const float4 e0 = *reinterpret_cast<const float4*>(&emb[(size_t)id * D_ + d0]);
    const float4 e1 = *reinterpret_cast<const float4*>(&emb[(size_t)id * D_ + d0 + 4]);
    const float4 t0 = *reinterpret_cast<const float4*>(&temb2[b * D_ + d0]);
    const float4 t1 = *reinterpret_cast<const float4*>(&temb2[b * D_ + d0 + 4]);
    float4 o0, o1;
    o0.x = e0.x + t0.x; o0.y = e0.y + t0.y; o0.z = e0.z + t0.z; o0.w = e0.w + t0.w;
    o1.x = e1.x + t1.x; o1.y = e1.y + t1.y; o1.z = e1.z + t1.z; o1.w = e1.w + t1.w;
    *reinterpret_cast<float4*>(&x[(size_t)row * D_ + d0]) = o0;
    *reinterpret_cast<float4*>(&x[(size_t)row * D_ + d0 + 4]) = o1;
}

// ---------- LayerNorm (f32 in, bf16 out) ----------
__global__ __launch_bounds__(256) void ln_kernel(const float* __restrict__ x,
                                                 const float* __restrict__ s,
                                                 const float* __restrict__ bb,
                                                 u16* __restrict__ out) {
    __shared__ float red[4];
    const int row = blockIdx.x, tid = threadIdx.x;
    const float4 v = *reinterpret_cast<const float4*>(x + (size_t)row * D_ + tid * 4);
    float sm = v.x + v.y + v.z + v.w;
#pragma unroll
    for (int o = 1; o < 64; o <<= 1) sm += __shfl_xor(sm, o);
    if ((tid & 63) == 0) red[tid >> 6] = sm;
    __syncthreads();
    const float mean = (red[0] + red[1] + red[2] + red[3]) * (1.f / 1024.f);
    __syncthreads();
    const float dx = v.x - mean, dy = v.y - mean, dz = v.z - mean, dw = v.w - mean;
    float sq = dx * dx + dy * dy + dz * dz + dw * dw;
#pragma unroll
    for (int o = 1; o < 64; o <<= 1) sq += __shfl_xor(sq, o);
    if ((tid & 63) == 0) red[tid >> 6] = sq;
    __syncthreads();
    const float var = (red[0] + red[1] + red[2] + red[3]) * (1.f / 1024.f);
    const float rs = rsqrtf(var + 1e-5f);
    const int c = tid * 4;
    const float4 sv = *reinterpret_cast<const float4*>(&s[c]);
    const float4 bv = *reinterpret_cast<const float4*>(&bb[c]);
    float4 o;
    o.x = dx * rs * sv.x + bv.x;
    o.y = dy * rs * sv.y + bv.y;
    o.z = dz * rs * sv.z + bv.z;
    o.w = dw * rs * sv.w + bv.w;
    *reinterpret_cast<uint2*>(&out[(size_t)row * D_ + c]) = f4_to_b4(o);
}

// ---------- chunked parallel selective scan, conv fused (sliding window) ----------
__global__ __launch_bounds__(256) void scan_p1(const u16* __restrict__ dt,
                                               const float* __restrict__ p,
                                               const u16* __restrict__ xr,
                                               const float* __restrict__ cw,
                                               const float* __restrict__ alog,
                                               float* __restrict__ Aprod,
                                               float* __restrict__ Hloc) {
    const int tid = threadIdx.x;
    const int ng = tid & 3;
    const int dl = tid >> 2;
    int blk = blockIdx.x;
    const int chunk = blk % SCAN_C; blk /= SCAN_C;
    const int dg = blk % (D_ / 64);
    const int b = blk / (D_ / 64);
    const int d = dg * 64 + dl;

    float a_v[4], inv_a[4];
#pragma unroll
    for (int j = 0; j < 4; ++j) {
        float av = -expf(alog[d * N_ + ng * 4 + j]);
        a_v[j] = av;
        inv_a[j] = 1.f / (av + 1e-10f);
    }
    const float4 cw4 = *reinterpret_cast<const float4*>(&cw[d * 4]);

    __shared__ float pbuf[SCAN_S * 32];
    const int t0 = chunk * SCAN_S;
    if (tid < SCAN_S * 8) {
        const int s = tid >> 3, off = (tid & 7) * 4;
        *reinterpret_cast<float4*>(&pbuf[s * 32 + off]) =
            *reinterpret_cast<const float4*>(&p[((size_t)(b * L_ + t0 + s)) * 96 + 64 + off]);
    }
    __syncthreads();

    const size_t base = (size_t)b * L_ * D_ + d;
    float xm3 = (t0 >= 3) ? b2f(xr[base + (size_t)(t0 - 3) * D_]) : 0.f;
    float xm2 = (t0 >= 2) ? b2f(xr[base + (size_t)(t0 - 2) * D_]) : 0.f;
    float xm1 = (t0 >= 1) ? b2f(xr[base + (size_t)(t0 - 1) * D_]) : 0.f;

    float A[4] = {1.f, 1.f, 1.f, 1.f};
    float h[4] = {0.f, 0.f, 0.f, 0.f};
#pragma unroll
    for (int s = 0; s < SCAN_S; ++s) {
        const size_t idx = base + (size_t)(t0 + s) * D_;
        const float xc = b2f(xr[idx]);
        const float uv = silu_f(cw4.x * xm3 + cw4.y * xm2 + cw4.z * xm1 + cw4.w * xc);
        xm3 = xm2; xm2 = xm1; xm1 = xc;
        const float dtv = b2f(dt[idx]);
#pragma unroll
        for (int j = 0; j < 4; ++j) {
            const float ex = fminf(dtv * a_v[j], 0.f);
            const float at = expf(ex);
            const float bt = (fabsf(a_v[j]) < 1e-8f) ? dtv : (at - 1.f) * inv_a[j];
            const float bp = pbuf[s * 32 + ng * 4 + j];
            A[j] *= at;
            h[j] = at * h[j] + bt * bp * uv;
        }
    }
    const size_t o = ((size_t)(b * SCAN_C + chunk) * D_ + d) * N_ + ng * 4;
    float4 a4 = {A[0], A[1], A[2], A[3]};
    float4 h4 = {h[0], h[1], h[2], h[3]};
    *reinterpret_cast<float4*>(&Aprod[o]) = a4;
    *reinterpret_cast<float4*>(&Hloc[o]) = h4;
}

__global__ __launch_bounds__(256) void scan_p2(const float* __restrict__ Aprod,
                                               const float* __restrict__ Hloc,
                                               float* __restrict__ Hstart) {
    const int gid = blockIdx.x * 256 + threadIdx.x;
    if (gid >= B_ * D_ * N_) return;
    const int b = gid / (D_ * N_);
    const int rem = gid % (D_ * N_);
    float H = 0.f;
#pragma unroll 8
    for (int k = 0; k < SCAN_C; ++k) {
        const size_t o = (size_t)(b * SCAN_C + k) * (D_ * N_) + rem;
        Hstart[o] = H;
        H = Aprod[o] * H + Hloc[o];
    }
}

__global__ __launch_bounds__(256) void scan_p3(const u16* __restrict__ dt,
                                               const float* __restrict__ p,
                                               const u16* __restrict__ xr,
                                               const float* __restrict__ cw,
                                               const u16* __restrict__ z,
                                               const float* __restrict__ alog,
                                               const float* __restrict__ Dp,
                                               const float* __restrict__ Hstart,
                                               u16* __restrict__ yg) {
    const int tid = threadIdx.x;
    const int ng = tid & 3;
    const int dl = tid >> 2;
    int blk = blockIdx.x;
    const int chunk = blk % SCAN_C; blk /= SCAN_C;
    const int dg = blk % (D_ / 64);
    const int b = blk / (D_ / 64);
    const int d = dg * 64 + dl;

    float a_v[4], inv_a[4];
#pragma unroll
    for (int j = 0; j < 4; ++j) {
        float av = -expf(alog[d * N_ + ng * 4 + j]);
        a_v[j] = av;
        inv_a[j] = 1.f / (av + 1e-10f);
    }
    const float Dpd = Dp[d];
    const float4 cw4 = *reinterpret_cast<const float4*>(&cw[d * 4]);

    __shared__ float pbuf[SCAN_S * 32];
    const int t0 = chunk * SCAN_S;
    if (tid < SCAN_S * 8) {
        const int s = tid >> 3, off = (tid & 7) * 4;
        *reinterpret_cast<float4*>(&pbuf[s * 32 + off]) =
            *reinterpret_cast<const float4*>(&p[((size_t)(b * L_ + t0 + s)) * 96 + 64 + off]);
    }
    __syncthreads();

    const size_t base = (size_t)b * L_ * D_ + d;
    float xm3 = (t0 >= 3) ? b2f(xr[base + (size_t)(t0 - 3) * D_]) : 0.f;
    float xm2 = (t0 >= 2) ? b2f(xr[base + (size_t)(t0 - 2) * D_]) : 0.f;
    float xm1 = (t0 >= 1) ? b2f(xr[base + (size_t)(t0 - 1) * D_]) : 0.f;

    float h[4];
    {
        const size_t o = ((size_t)(b * SCAN_C + chunk) * D_ + d) * N_ + ng * 4;
        const float4 h4 = *reinterpret_cast<const float4*>(&Hstart[o]);
        h[0] = h4.x; h[1] = h4.y; h[2] = h4.z; h[3] = h4.w;
    }

#pragma unroll
    for (int s = 0; s < SCAN_S; ++s) {
        const size_t idx = base + (size_t)(t0 + s) * D_;
        const float xc = b2f(xr[idx]);
        const float uv = silu_f(cw4.x * xm3 + cw4.y * xm2 + cw4.z * xm1 + cw4.w * xc);
        xm3 = xm2; xm2 = xm1; xm1 = xc;
        const float dtv = b2f(dt[idx]);
        float yp = 0.f;
#pragma unroll
        for (int j = 0; j < 4; ++j) {
            const float ex = fminf(dtv * a_v[j], 0.f);
            const float at = expf(ex);
            const float bt = (fabsf(a_v[j]) < 1e-8f) ? dtv : (at - 1.f) * inv_a[j];
            const float bp = pbuf[s * 32 + ng * 4 + j];
            const float cp = pbuf[s * 32 + 16 + ng * 4 + j];
            h[j] = at * h[j] + bt * bp * uv;
            yp += cp * h[j];
        }
        yp += __shfl_xor(yp, 1);
        yp += __shfl_xor(yp, 2);
        if (ng == 0) {
            const float zv = b2f(z[idx]);
            yg[idx] = f2b((yp + uv * Dpd) * silu_f(zv));
        }
    }
}

// ---------- launch ----------
extern "C" void kernel_launch(void* const* d_in, const int* in_sizes, int n_in,
                              void* d_out, int out_size, void* d_ws, size_t ws_size,
                              hipStream_t stream) {
    (void)in_sizes; (void)n_in; (void)out_size;
    const int* ids = (const int*)d_in[0];
    const int* tsteps = (const int*)d_in[1];
    const float* emb = (const float*)d_in[2];
    const float* tw1 = (const float*)d_in[3];
    const float* tb1 = (const float*)d_in[4];
    const float* tw2 = (const float*)d_in[5];
    const float* tb2 = (const float*)d_in[6];
    const float* ln1s = (const float*)d_in[7];
    const float* ln1b = (const float*)d_in[8];
    const float* wx = (const float*)d_in[9];
    const float* wz = (const float*)d_in[10];
    const float* wp = (const float*)d_in[11];
    const float* convw = (const float*)d_in[12];
    const float* dtw = (const float*)d_in[13];
    const float* dtb = (const float*)d_in[14];
    const float* alog = (const float*)d_in[15];
    const float* dp = (const float*)d_in[16];
    const float* wo = (const float*)d_in[17];
    const float* ln2s = (const float*)d_in[18];
    const float* ln2b = (const float*)d_in[19];
    const float* mw1 = (const float*)d_in[20];
    const float* mb1 = (const float*)d_in[21];
    const float* mw2 = (const float*)d_in[22];
    const float* mb2 = (const float*)d_in[23];
    const float* lnos = (const float*)d_in[24];
    const float* lnob = (const float*)d_in[25];
    const float* hw = (const float*)d_in[26];
    const float* hb = (const float*)d_in[27];
    float* outp = (float*)d_out;

    char* w = (char*)d_ws;
    size_t used = 0;
    auto alloc = [&](size_t bytes) {
        char* pp = w;
        size_t rb = (bytes + 255) & ~(size_t)255;
        w += rb;
        used += rb;
        return pp;
    };
    float* x = (float*)alloc((size_t)MROWS * D_ * 4);
    float* t0f = (float*)alloc((size_t)B_ * D_ * 4);
    float* t1f = (float*)alloc((size_t)B_ * MLP_ * 4);
    float* t2f = (float*)alloc((size_t)B_ * D_ * 4);
    u16* xnb = (u16*)alloc((size_t)MROWS * D_ * 2);
    u16* xres = (u16*)alloc((size_t)MROWS * D_ * 2);
    u16* zb = (u16*)alloc((size_t)MROWS * D_ * 2);
    float* pf = (float*)alloc((size_t)MROWS * 96 * 4);
    u16* dtb16 = (u16*)alloc((size_t)MROWS * D_ * 2);
    u16* ygb = (u16*)alloc((size_t)MROWS * D_ * 2);
    const bool cvt_head = (ws_size >= used + (size_t)V_ * D_ * 2 + 4096);
    u16* hwb = cvt_head ? (u16*)alloc((size_t)V_ * D_ * 2) : nullptr;
    const size_t lw_bytes = ((size_t)DEPTH_ * D_ * D_ * 3 + (size_t)DEPTH_ * 96 * D_ +
                             (size_t)DEPTH_ * D_ * R_ + (size_t)DEPTH_ * MLP_ * D_ * 2) * 2;
    const bool cvt_layer = cvt_head && (ws_size >= used + lw_bytes + ((size_t)1 << 20));
    u16 *wxb = nullptr, *wzb = nullptr, *wpb = nullptr, *dtwb = nullptr, *wob = nullptr,
        *mw1b = nullptr, *mw2b = nullptr;
    if (cvt_layer) {
        wxb = (u16*)alloc((size_t)DEPTH_ * D_ * D_ * 2);
        wzb = (u16*)alloc((size_t)DEPTH_ * D_ * D_ * 2);
        wpb = (u16*)alloc((size_t)DEPTH_ * 96 * D_ * 2);
        dtwb = (u16*)alloc((size_t)DEPTH_ * D_ * R_ * 2);
        wob = (u16*)alloc((size_t)DEPTH_ * D_ * D_ * 2);
        mw1b = (u16*)alloc((size_t)DEPTH_ * MLP_ * D_ * 2);
        mw2b = (u16*)alloc((size_t)DEPTH_ * MLP_ * D_ * 2);
    }
    u16* m1b = (u16*)outp;  // MLP hidden scratch in d_out (overwritten by head)
    float* Aprod = outp + (size_t)6 * 1024 * 1024;
    float* Hloc = outp + (size_t)8 * 1024 * 1024;
    float* Hstart = outp + (size_t)10 * 1024 * 1024;

    auto cvt = [&](const float* src, u16* dst, size_t n) {
        cvt_kernel<<<dim3((unsigned)((n / 8 + 255) / 256)), dim3(256), 0, stream>>>(src, dst,
                                                                                   (int)(n / 8));
    };
    if (cvt_head) cvt(hw, hwb, (size_t)V_ * D_);
    if (cvt_layer) {
        cvt(wx, wxb, (size_t)DEPTH_ * D_ * D_);
        cvt(wz, wzb, (size_t)DEPTH_ * D_ * D_);
        cvt(wp, wpb, (size_t)DEPTH_ * 96 * D_);
        cvt(dtw, dtwb, (size_t)DEPTH_ * D_ * R_);
        cvt(wo, wob, (size_t)DEPTH_ * D_ * D_);
        cvt(mw1, mw1b, (size_t)DEPTH_ * MLP_ * D_);
        cvt(mw2, mw2b, (size_t)DEPTH_ * MLP_ * D_);
    }
    temb0_kernel<<<dim3((B_ * D_ + 255) / 256), dim3(256), 0, stream>>>(tsteps, t0f);
    rowdot_kernel<1><<<dim3(B_ * MLP_ / 4), dim3(256), 0, stream>>>(t0f, tw1, tb1, t1f, MLP_, D_);
    rowdot_kernel<0><<<dim3(B_ * D_ / 4), dim3(256), 0, stream>>>(t1f, tw2, tb2, t2f, D_, MLP_);
    embed_kernel<<<dim3(MROWS * D_ / 8 / 256), dim3(256), 0, stream>>>(ids, emb, t2f, x);

    for (int i = 0; i < DEPTH_; ++i) {
        const float* cwi = convw + (size_t)i * D_ * 4;
        const float* dtbi = dtb + (size_t)i * D_;
        const float* ali = alog + (size_t)i * D_ * N_;
        const float* dpi = dp + (size_t)i * D_;
        const float* mb1i = mb1 + (size_t)i * MLP_;
        const float* mb2i = mb2 + (size_t)i * D_;

        ln_kernel<<<dim3(MROWS), dim3(256), 0, stream>>>(x, ln1s + i * D_, ln1b + i * D_, xnb);
        if (cvt_layer) {
            gemm_bt<32, 64, 0, 0, 1, u16, u16, u16><<<dim3(1024), dim3(256), 0, stream>>>(
                xnb, D_, wxb + (size_t)i * D_ * D_, wzb + (size_t)i * D_ * D_, nullptr,
                xres, zb, D_, D_, 32);
            gemm_bt<32, 64, 0, 0, 1, u16, u16, float><<<dim3(64), dim3(256), 0, stream>>>(
                xnb, D_, wpb + (size_t)i * 96 * D_, nullptr, nullptr, pf, nullptr, 96, D_, 2);
            gemm_bt<32, 64, 2, 0, 0, float, u16, u16><<<dim3(512), dim3(256), 0, stream>>>(
                pf, 96, dtwb + (size_t)i * D_ * R_, nullptr, dtbi, dtb16, nullptr, D_, R_, 16);
        } else {
            gemm_bt<32, 64, 0, 0, 0, u16, float, u16><<<dim3(1024), dim3(256), 0, stream>>>(
                xnb, D_, wx + (size_t)i * D_ * D_, wz + (size_t)i * D_ * D_, nullptr,
                xres, zb, D_, D_, 32);
            gemm_bt<32, 64, 0, 0, 0, u16, float, float><<<dim3(64), dim3(256), 0, stream>>>(
                xnb, D_, wp + (size_t)i * 96 * D_, nullptr, nullptr, pf, nullptr, 96, D_, 2);
            gemm_bt<32, 64, 2, 0, 0, float, float, u16><<<dim3(512), dim3(256), 0, stream>>>(
                pf, 96, dtw + (size_t)i * D_ * R_, nullptr, dtbi, dtb16, nullptr, D_, R_, 16);
        }
        scan_p1<<<dim3(B_ * (D_ / 64) * SCAN_C), dim3(256), 0, stream>>>(
            dtb16, pf, xres, cwi, ali, Aprod, Hloc);
        scan_p2<<<dim3(B_ * D_ * N_ / 256), dim3(256), 0, stream>>>(Aprod, Hloc, Hstart);
        scan_p3<<<dim3(B_ * (D_ / 64) * SCAN_C), dim3(256), 0, stream>>>(
            dtb16, pf, xres, cwi, zb, ali, dpi, Hstart, ygb);
        if (cvt_layer) {
            gemm_bt<32, 64, 0, 1, 1, u16, u16, float><<<dim3(512), dim3(256), 0, stream>>>(
                ygb, D_, wob + (size_t)i * D_ * D_, nullptr, nullptr, x, nullptr, D_, D_, 16);
        } else {
            gemm_bt<32, 64, 0, 1, 0, u16, float, float><<<dim3(512), dim3(256), 0, stream>>>(
                ygb, D_, wo + (size_t)i * D_ * D_, nullptr, nullptr, x, nullptr, D_, D_, 16);
        }
        ln_kernel<<<dim3(MROWS), dim3(256), 0, stream>>>(x, ln2s + i * D_, ln2b + i * D_, xnb);
        if (cvt_layer) {
            gemm_bt<32, 64, 1, 0, 1, u16, u16, u16><<<dim3(2048), dim3(256), 0, stream>>>(
                xnb, D_, mw1b + (size_t)i * MLP_ * D_, nullptr, mb1i, m1b, nullptr, MLP_, D_, 64);
            gemm_bt<32, 64, 0, 1, 1, u16, u16, float><<<dim3(512), dim3(256), 0, stream>>>(
                m1b, MLP_, mw2b + (size_t)i * MLP_ * D_, nullptr, mb2i, x, nullptr, D_, MLP_, 16);
        } else {
            gemm_bt<32, 64, 1, 0, 0, u16, float, u16><<<dim3(2048), dim3(256), 0, stream>>>(
                xnb, D_, mw1 + (size_t)i * MLP_ * D_, nullptr, mb1i, m1b, nullptr, MLP_, D_, 64);
            gemm_bt<32, 64, 0, 1, 0, u16, float, float><<<dim3(512), dim3(256), 0, stream>>>(
                m1b, MLP_, mw2 + (size_t)i * MLP_ * D_, nullptr, mb2i, x, nullptr, D_, MLP_, 16);
        }
    }

    ln_kernel<<<dim3(MROWS), dim3(256), 0, stream>>>(x, lnos, lnob, xnb);
    // head: r13 config (single-buffered DMA, BM=128/BN=128, n-major) — 183 us measured.
    constexpr int HNT = (V_ + 127) / 128;  // 391
    if (cvt_head) {
        gemm_bt<128, 128, 0, 0, 0, u16, u16, float>
            <<<dim3(8 * HNT), dim3(256), 0, stream>>>(
                xnb, D_, hwb, (const u16*)nullptr, hb, outp, nullptr, V_, D_, HNT);
    } else {
        gemm_bt<128, 128, 0, 0, 0, u16, float, float>
            <<<dim3(8 * HNT), dim3(256), 0, stream>>>(
                xnb, D_, hw, (const float*)nullptr, hb, outp, nullptr, V_, D_, HNT);
    }
}

// Round 20
// 932.511 us; speedup vs baseline: 1.1440x; 1.1302x over previous
//
#include <hip/hip_runtime.h>

typedef unsigned short u16;
typedef __attribute__((ext_vector_type(8))) __bf16 bf16x8;
typedef __attribute__((ext_vector_type(4))) float floatx4;

#define B_ 2
#define L_ 512
#define D_ 1024
#define N_ 16
#define R_ 64
#define DEPTH_ 4
#define V_ 50000
#define MLP_ 4096
#define MROWS (B_ * L_)
#define SCAN_C 32
#define SCAN_S (L_ / SCAN_C)  // 16

// LDS XOR swizzle for 128-byte rows (BK=64 bf16). Involution: SWZ(SWZ(b)) == b.
#define SWZ(b) ((b) ^ ((((b) >> 7) & 7) << 4))

// ---------- helpers ----------
__device__ __forceinline__ float b2f(u16 u) {
    unsigned int i = ((unsigned int)u) << 16;
    return __builtin_bit_cast(float, i);
}
__device__ __forceinline__ u16 f2b(float f) {
    return __builtin_bit_cast(u16, (__bf16)f);
}
__device__ __forceinline__ uint2 f4_to_b4(float4 v) {
    u16 a = f2b(v.x), b = f2b(v.y), c = f2b(v.z), d = f2b(v.w);
    uint2 r;
    r.x = (unsigned int)a | ((unsigned int)b << 16);
    r.y = (unsigned int)c | ((unsigned int)d << 16);
    return r;
}
__device__ __forceinline__ void async16(const void* g, void* l) {
    __builtin_amdgcn_global_load_lds(
        (const __attribute__((address_space(1))) void*)g,
        (__attribute__((address_space(3))) void*)l, 16, 0, 0);
}
template <int Ncnt>
__device__ __forceinline__ void waitcnt_vm() {
    if constexpr (Ncnt == 0) asm volatile("s_waitcnt vmcnt(0)" ::: "memory");
    else if constexpr (Ncnt == 2) asm volatile("s_waitcnt vmcnt(2)" ::: "memory");
    else if constexpr (Ncnt == 3) asm volatile("s_waitcnt vmcnt(3)" ::: "memory");
    else if constexpr (Ncnt == 4) asm volatile("s_waitcnt vmcnt(4)" ::: "memory");
    else if constexpr (Ncnt == 6) asm volatile("s_waitcnt vmcnt(6)" ::: "memory");
    else if constexpr (Ncnt == 8) asm volatile("s_waitcnt vmcnt(8)" ::: "memory");
    else asm volatile("s_waitcnt vmcnt(0)" ::: "memory");
}
__device__ __forceinline__ float silu_f(float v) { return v / (1.f + expf(-v)); }
__device__ __forceinline__ float gelu_f(float v) {
    return 0.5f * v * (1.f + erff(v * 0.7071067811865476f));
}
__device__ __forceinline__ float softplus_f(float v) {
    return fmaxf(v, 0.f) + log1pf(expf(-fabsf(v)));
}

// ---------- f32 -> bf16 bulk convert ----------
__global__ __launch_bounds__(256) void cvt_kernel(const float* __restrict__ in,
                                                  u16* __restrict__ out, const int n8) {
    const int i = blockIdx.x * 256 + threadIdx.x;
    if (i >= n8) return;
    const float4 a = *reinterpret_cast<const float4*>(&in[(size_t)i * 8]);
    const float4 b = *reinterpret_cast<const float4*>(&in[(size_t)i * 8 + 4]);
    uint4 o;
    uint2 lo = f4_to_b4(a), hi = f4_to_b4(b);
    o.x = lo.x; o.y = lo.y; o.z = hi.x; o.w = hi.y;
    *reinterpret_cast<uint4*>(&out[(size_t)i * 8]) = o;
}

// ---------- MFMA GEMM: C[M,N] = act(A[M,K] @ W[N,K]^T + bias) ----------
// PIPEOK && both-u16: double-buffered DMA + counted vmcnt pipeline.
// Else: single-buffered (DMA for u16, reg-cvt for f32).
// gsz>0: supertile mapping (n-panel groups of gsz; all m-tiles inner) for L3 W reuse.
template <int BM, int BN, int ACT, int RES, int PIPEOK, typename AT, typename WT, typename OUT>
__global__ __launch_bounds__(256) void gemm_bt(
    const AT* __restrict__ A, const int lda,
    const WT* __restrict__ W, const WT* __restrict__ W2,
    const float* __restrict__ bias,
    OUT* __restrict__ out, OUT* __restrict__ out2,
    const int N, const int K, const int nt, const int gsz) {
    constexpr int BK = 64;
    constexpr int MI = BM / 32;
    constexpr int NI = BN / 32;
    constexpr int WM = BM / 2;
    constexpr bool PIPE = PIPEOK && (sizeof(AT) == 2) && (sizeof(WT) == 2);
    __shared__ alignas(16) u16 lA[(PIPE ? 2 : 1) * BM * BK];
    __shared__ alignas(16) u16 lW[(PIPE ? 2 : 1) * BN * BK];
    const int tid = threadIdx.x;
    const int lane = tid & 63, wv = tid >> 6;
    const int bid = blockIdx.x;

    int mI, nI;
    if (gsz > 0) {
        const int mtt = gridDim.x / nt;
        const int fullG = nt / gsz;
        const int fullBlocks = fullG * gsz * mtt;
        if (bid < fullBlocks) {
            const int per = gsz * mtt;
            const int g = bid / per, r = bid % per;
            mI = r / gsz;
            nI = g * gsz + r % gsz;
        } else {
            const int rem = nt - fullG * gsz;
            const int r = bid - fullBlocks;
            mI = r / rem;
            nI = fullG * gsz + r % rem;
        }
    } else {
        mI = bid / nt;
        nI = bid % nt;
    }
    const int m0 = mI * BM;
    int n0 = nI * BN;
    const WT* Wp = W;
    OUT* op = out;
    if (W2 != nullptr && n0 >= N) {
        Wp = W2;
        op = out2;
        n0 -= N;
    }
    const int wr = wv >> 1, wc = wv & 1;
    const int lr = lane & 15, kg = lane >> 4;

    floatx4 acc[MI][NI];
#pragma unroll
    for (int i = 0; i < MI; ++i)
#pragma unroll
        for (int j = 0; j < NI; ++j) {
            floatx4 z4 = {0.f, 0.f, 0.f, 0.f};
            acc[i][j] = z4;
        }

    const int T = K / BK;

    if constexpr (PIPE) {
        constexpr int NEWER = BM / 32 + BN / 32;
        auto issue = [&](int t) {
            const int buf = t & 1;
            const int kt = t * BK;
#pragma unroll
            for (int c = wv; c < BM / 8; c += 4) {
                const int dst = c * 1024 + lane * 16;
                const int lg = SWZ(dst);
                const int row = lg >> 7, colb = lg & 127;
                async16((const char*)A + ((size_t)(m0 + row) * lda + kt) * 2 + colb,
                        (char*)lA + buf * BM * 128 + c * 1024);
            }
#pragma unroll
            for (int c = wv; c < BN / 8; c += 4) {
                const int dst = c * 1024 + lane * 16;
                const int lg = SWZ(dst);
                const int row = lg >> 7, colb = lg & 127;
                int rn = n0 + row;
                rn = (rn < N) ? rn : (N - 1);
                async16((const char*)Wp + ((size_t)rn * K + kt) * 2 + colb,
                        (char*)lW + buf * BN * 128 + c * 1024);
            }
        };
        issue(0);
        for (int t = 0; t < T; ++t) {
            if (t + 1 < T) {
                issue(t + 1);
                waitcnt_vm<NEWER>();
            } else {
                waitcnt_vm<0>();
            }
            __builtin_amdgcn_s_barrier();
            __builtin_amdgcn_sched_barrier(0);
            const char* bA = (const char*)lA + (t & 1) * BM * 128;
            const char* bW = (const char*)lW + (t & 1) * BN * 128;
#pragma unroll
            for (int kk = 0; kk < 2; ++kk) {
                bf16x8 aF[MI], bF[NI];
#pragma unroll
                for (int mi = 0; mi < MI; ++mi)
                    aF[mi] = *reinterpret_cast<const bf16x8*>(
                        bA + SWZ((wr * WM + mi * 16 + lr) * 128 + kk * 64 + kg * 16));
#pragma unroll
                for (int ni = 0; ni < NI; ++ni)
                    bF[ni] = *reinterpret_cast<const bf16x8*>(
                        bW + SWZ((wc * (BN / 2) + ni * 16 + lr) * 128 + kk * 64 + kg * 16));
#pragma unroll
                for (int mi = 0; mi < MI; ++mi)
#pragma unroll
                    for (int ni = 0; ni < NI; ++ni)
                        acc[mi][ni] = __builtin_amdgcn_mfma_f32_16x16x32_bf16(
                            aF[mi], bF[ni], acc[mi][ni], 0, 0, 0);
            }
            __builtin_amdgcn_sched_barrier(0);
            if (t + 1 < T) __builtin_amdgcn_s_barrier();
        }
    } else {
        for (int t = 0; t < T; ++t) {
            const int kt = t * BK;
            if (t) __syncthreads();
            if constexpr (sizeof(AT) == 2) {
#pragma unroll
                for (int c = wv; c < BM / 8; c += 4) {
                    const int dst = c * 1024 + lane * 16;
                    const int lg = SWZ(dst);
                    const int row = lg >> 7, colb = lg & 127;
                    async16((const char*)A + ((size_t)(m0 + row) * lda + kt) * 2 + colb,
                            (char*)lA + c * 1024);
                }
            } else {
                constexpr int ACHF = (BM * BK) / 1024;
                float4 raF[ACHF];
#pragma unroll
                for (int i = 0; i < ACHF; ++i) {
                    const int idx = tid + i * 256;
                    const int row = idx >> 4, c4 = (idx & 15) * 4;
                    raF[i] = *reinterpret_cast<const float4*>(&A[(size_t)(m0 + row) * lda + kt + c4]);
                }
#pragma unroll
                for (int i = 0; i < ACHF; ++i) {
                    const int idx = tid + i * 256;
                    const int row = idx >> 4, c4 = (idx & 15) * 4;
                    *reinterpret_cast<uint2*>((char*)lA + SWZ(row * 128 + c4 * 2)) = f4_to_b4(raF[i]);
                }
            }
            if constexpr (sizeof(WT) == 2) {
#pragma unroll
                for (int c = wv; c < BN / 8; c += 4) {
                    const int dst = c * 1024 + lane * 16;
                    const int lg = SWZ(dst);
                    const int row = lg >> 7, colb = lg & 127;
                    int rn = n0 + row;
                    rn = (rn < N) ? rn : (N - 1);
                    async16((const char*)Wp + ((size_t)rn * K + kt) * 2 + colb,
                            (char*)lW + c * 1024);
                }
            } else {
                constexpr int WCHF = (BN * BK) / 1024;
                float4 rwF[WCHF];
#pragma unroll
                for (int i = 0; i < WCHF; ++i) {
                    const int idx = tid + i * 256;
                    const int row = idx >> 4, c4 = (idx & 15) * 4;
                    int rn = n0 + row;
                    rn = (rn < N) ? rn : (N - 1);
                    rwF[i] = *reinterpret_cast<const float4*>(&Wp[(size_t)rn * K + kt + c4]);
                }
#pragma unroll
                for (int i = 0; i < WCHF; ++i) {
                    const int idx = tid + i * 256;
                    const int row = idx >> 4, c4 = (idx & 15) * 4;
                    *reinterpret_cast<uint2*>((char*)lW + SWZ(row * 128 + c4 * 2)) = f4_to_b4(rwF[i]);
                }
            }
            __syncthreads();
#pragma unroll
            for (int kk = 0; kk < 2; ++kk) {
                bf16x8 aF[MI], bF[NI];
#pragma unroll
                for (int mi = 0; mi < MI; ++mi)
                    aF[mi] = *reinterpret_cast<const bf16x8*>(
                        (const char*)lA + SWZ((wr * WM + mi * 16 + lr) * 128 + kk * 64 + kg * 16));
#pragma unroll
                for (int ni = 0; ni < NI; ++ni)
                    bF[ni] = *reinterpret_cast<const bf16x8*>(
                        (const char*)lW + SWZ((wc * (BN / 2) + ni * 16 + lr) * 128 + kk * 64 + kg * 16));
#pragma unroll
                for (int mi = 0; mi < MI; ++mi)
#pragma unroll
                    for (int ni = 0; ni < NI; ++ni)
                        acc[mi][ni] = __builtin_amdgcn_mfma_f32_16x16x32_bf16(
                            aF[mi], bF[ni], acc[mi][ni], 0, 0, 0);
            }
        }
    }

    // epilogue: D layout col = lane&15, row = (lane>>4)*4 + r; mi->r->ni order.
#pragma unroll
    for (int mi = 0; mi < MI; ++mi) {
        const int rb = m0 + wr * WM + mi * 16 + kg * 4;
#pragma unroll
        for (int r = 0; r < 4; ++r) {
            const size_t rowoff = (size_t)(rb + r) * (size_t)N;
#pragma unroll
            for (int ni = 0; ni < NI; ++ni) {
                const int col = n0 + wc * (BN / 2) + ni * 16 + lr;
                if (col >= N) continue;
                float v = acc[mi][ni][r] + (bias ? bias[col] : 0.f);
                if constexpr (ACT == 1) v = gelu_f(v);
                if constexpr (ACT == 2) v = softplus_f(v);
                const size_t o = rowoff + (size_t)col;
                if constexpr (RES) {
                    op[o] += v;
                } else if constexpr (sizeof(OUT) == 2) {
                    op[o] = f2b(v);
                } else {
                    op[o] = v;
                }
            }
        }
    }
}

// ---------- timestep embedding base ----------
__global__ __launch_bounds__(256) void temb0_kernel(const int* __restrict__ ts,
                                                    float* __restrict__ temb0) {
    int i = blockIdx.x * 256 + threadIdx.x;
    if (i >= B_ * D_) return;
    int b = i >> 10, k = i & 1023;
    float t = (float)ts[b];
    int h = (k < 512) ? k : (k - 512);
    float f = expf((float)h * (-9.210340371976184f / 511.f));
    float e = t * f;
    temb0[i] = (k < 512) ? sinf(e) : cosf(e);
}

// ---------- small row-dot GEMM (M=B) ----------
template <int ACTV>
__global__ __launch_bounds__(256) void rowdot_kernel(const float* __restrict__ in,
                                                     const float* __restrict__ W,
                                                     const float* __restrict__ bias,
                                                     float* __restrict__ out,
                                                     const int Ncols, const int K) {
    const int g = (blockIdx.x * 256 + threadIdx.x) >> 6;
    const int lane = threadIdx.x & 63;
    if (g >= B_ * Ncols) return;
    const int b = g / Ncols, j = g % Ncols;
    const float* xr = in + (size_t)b * K;
    const float* wr = W + (size_t)j * K;
    float s = 0.f;
    for (int k = lane; k < K; k += 64) s += xr[k] * wr[k];
#pragma unroll
    for (int o = 32; o; o >>= 1) s += __shfl_xor(s, o);
    if (lane == 0) {
        float v = s + bias[j];
        if (ACTV == 1) v = silu_f(v);
        out[(size_t)b * Ncols + j] = v;
    }
}

// ---------- embedding + temb broadcast ----------
__global__ __launch_bounds__(256) void embed_kernel(const int* __restrict__ ids,
                                                    const float* __restrict__ emb,
                                                    const float* __restrict__ temb2,
                                                    float* __restrict__ x) {
    const int gid = blockIdx.x * 256 + threadIdx.x;
    const int d8 = gid & 127;
    const int row = gid >> 7;
    const int b = row >> 9;
    const int d0 = d8 * 8;
    const int id = ids[row];
    const float4 e0 = *reinterpret_cast<const float4*>(&emb[(size_t)id * D_ + d0]);
    const float4 e1 = *reinterpret_cast<const float4*>(&emb[(size_t)id * D_ + d0 + 4]);
    const float4 t0 = *reinterpret_cast<const float4*>(&temb2[b * D_ + d0]);
    const float4 t1 = *reinterpret_cast<const float4*>(&temb2[b * D_ + d0 + 4]);
    float4 o0, o1;
    o0.x = e0.x + t0.x; o0.y = e0.y + t0.y; o0.z = e0.z + t0.z; o0.w = e0.w + t0.w;
    o1.x = e1.x + t1.x; o1.y = e1.y + t1.y; o1.z = e1.z + t1.z; o1.w = e1.w + t1.w;
    *reinterpret_cast<float4*>(&x[(size_t)row * D_ + d0]) = o0;
    *reinterpret_cast<float4*>(&x[(size_t)row * D_ + d0 + 4]) = o1;
}

// ---------- LayerNorm (f32 in, bf16 out) ----------
__global__ __launch_bounds__(256) void ln_kernel(const float* __restrict__ x,
                                                 const float* __restrict__ s,
                                                 const float* __restrict__ bb,
                                                 u16* __restrict__ out) {
    __shared__ float red[4];
    const int row = blockIdx.x, tid = threadIdx.x;
    const float4 v = *reinterpret_cast<const float4*>(x + (size_t)row * D_ + tid * 4);
    float sm = v.x + v.y + v.z + v.w;
#pragma unroll
    for (int o = 1; o < 64; o <<= 1) sm += __shfl_xor(sm, o);
    if ((tid & 63) == 0) red[tid >> 6] = sm;
    __syncthreads();
    const float mean = (red[0] + red[1] + red[2] + red[3]) * (1.f / 1024.f);
    __syncthreads();
    const float dx = v.x - mean, dy = v.y - mean, dz = v.z - mean, dw = v.w - mean;
    float sq = dx * dx + dy * dy + dz * dz + dw * dw;
#pragma unroll
    for (int o = 1; o < 64; o <<= 1) sq += __shfl_xor(sq, o);
    if ((tid & 63) == 0) red[tid >> 6] = sq;
    __syncthreads();
    const float var = (red[0] + red[1] + red[2] + red[3]) * (1.f / 1024.f);
    const float rs = rsqrtf(var + 1e-5f);
    const int c = tid * 4;
    const float4 sv = *reinterpret_cast<const float4*>(&s[c]);
    const float4 bv = *reinterpret_cast<const float4*>(&bb[c]);
    float4 o;
    o.x = dx * rs * sv.x + bv.x;
    o.y = dy * rs * sv.y + bv.y;
    o.z = dz * rs * sv.z + bv.z;
    o.w = dw * rs * sv.w + bv.w;
    *reinterpret_cast<uint2*>(&out[(size_t)row * D_ + c]) = f4_to_b4(o);
}

// ---------- chunked parallel selective scan, conv fused (sliding window) ----------
__global__ __launch_bounds__(256) void scan_p1(const u16* __restrict__ dt,
                                               const float* __restrict__ p,
                                               const u16* __restrict__ xr,
                                               const float* __restrict__ cw,
                                               const float* __restrict__ alog,
                                               float* __restrict__ Aprod,
                                               float* __restrict__ Hloc) {
    const int tid = threadIdx.x;
    const int ng = tid & 3;
    const int dl = tid >> 2;
    int blk = blockIdx.x;
    const int chunk = blk % SCAN_C; blk /= SCAN_C;
    const int dg = blk % (D_ / 64);
    const int b = blk / (D_ / 64);
    const int d = dg * 64 + dl;

    float a_v[4], inv_a[4];
#pragma unroll
    for (int j = 0; j < 4; ++j) {
        float av = -expf(alog[d * N_ + ng * 4 + j]);
        a_v[j] = av;
        inv_a[j] = 1.f / (av + 1e-10f);
    }
    const float4 cw4 = *reinterpret_cast<const float4*>(&cw[d * 4]);

    __shared__ float pbuf[SCAN_S * 32];
    const int t0 = chunk * SCAN_S;
    if (tid < SCAN_S * 8) {
        const int s = tid >> 3, off = (tid & 7) * 4;
        *reinterpret_cast<float4*>(&pbuf[s * 32 + off]) =
            *reinterpret_cast<const float4*>(&p[((size_t)(b * L_ + t0 + s)) * 96 + 64 + off]);
    }
    __syncthreads();

    const size_t base = (size_t)b * L_ * D_ + d;
    float xm3 = (t0 >= 3) ? b2f(xr[base + (size_t)(t0 - 3) * D_]) : 0.f;
    float xm2 = (t0 >= 2) ? b2f(xr[base + (size_t)(t0 - 2) * D_]) : 0.f;
    float xm1 = (t0 >= 1) ? b2f(xr[base + (size_t)(t0 - 1) * D_]) : 0.f;

    float A[4] = {1.f, 1.f, 1.f, 1.f};
    float h[4] = {0.f, 0.f, 0.f, 0.f};
#pragma unroll
    for (int s = 0; s < SCAN_S; ++s) {
        const size_t idx = base + (size_t)(t0 + s) * D_;
        const float xc = b2f(xr[idx]);
        const float uv = silu_f(cw4.x * xm3 + cw4.y * xm2 + cw4.z * xm1 + cw4.w * xc);
        xm3 = xm2; xm2 = xm1; xm1 = xc;
        const float dtv = b2f(dt[idx]);
#pragma unroll
        for (int j = 0; j < 4; ++j) {
            const float ex = fminf(dtv * a_v[j], 0.f);
            const float at = expf(ex);
            const float bt = (fabsf(a_v[j]) < 1e-8f) ? dtv : (at - 1.f) * inv_a[j];
            const float bp = pbuf[s * 32 + ng * 4 + j];
            A[j] *= at;
            h[j] = at * h[j] + bt * bp * uv;
        }
    }
    const size_t o = ((size_t)(b * SCAN_C + chunk) * D_ + d) * N_ + ng * 4;
    float4 a4 = {A[0], A[1], A[2], A[3]};
    float4 h4 = {h[0], h[1], h[2], h[3]};
    *reinterpret_cast<float4*>(&Aprod[o]) = a4;
    *reinterpret_cast<float4*>(&Hloc[o]) = h4;
}

__global__ __launch_bounds__(256) void scan_p2(const float* __restrict__ Aprod,
                                               const float* __restrict__ Hloc,
                                               float* __restrict__ Hstart) {
    const int gid = blockIdx.x * 256 + threadIdx.x;
    if (gid >= B_ * D_ * N_) return;
    const int b = gid / (D_ * N_);
    const int rem = gid % (D_ * N_);
    float H = 0.f;
#pragma unroll 8
    for (int k = 0; k < SCAN_C; ++k) {
        const size_t o = (size_t)(b * SCAN_C + k) * (D_ * N_) + rem;
        Hstart[o] = H;
        H = Aprod[o] * H + Hloc[o];
    }
}

__global__ __launch_bounds__(256) void scan_p3(const u16* __restrict__ dt,
                                               const float* __restrict__ p,
                                               const u16* __restrict__ xr,
                                               const float* __restrict__ cw,
                                               const u16* __restrict__ z,
                                               const float* __restrict__ alog,
                                               const float* __restrict__ Dp,
                                               const float* __restrict__ Hstart,
                                               u16* __restrict__ yg) {
    const int tid = threadIdx.x;
    const int ng = tid & 3;
    const int dl = tid >> 2;
    int blk = blockIdx.x;
    const int chunk = blk % SCAN_C; blk /= SCAN_C;
    const int dg = blk % (D_ / 64);
    const int b = blk / (D_ / 64);
    const int d = dg * 64 + dl;

    float a_v[4], inv_a[4];
#pragma unroll
    for (int j = 0; j < 4; ++j) {
        float av = -expf(alog[d * N_ + ng * 4 + j]);
        a_v[j] = av;
        inv_a[j] = 1.f / (av + 1e-10f);
    }
    const float Dpd = Dp[d];
    const float4 cw4 = *reinterpret_cast<const float4*>(&cw[d * 4]);

    __shared__ float pbuf[SCAN_S * 32];
    const int t0 = chunk * SCAN_S;
    if (tid < SCAN_S * 8) {
        const int s = tid >> 3, off = (tid & 7) * 4;
        *reinterpret_cast<float4*>(&pbuf[s * 32 + off]) =
            *reinterpret_cast<const float4*>(&p[((size_t)(b * L_ + t0 + s)) * 96 + 64 + off]);
    }
    __syncthreads();

    const size_t base = (size_t)b * L_ * D_ + d;
    float xm3 = (t0 >= 3) ? b2f(xr[base + (size_t)(t0 - 3) * D_]) : 0.f;
    float xm2 = (t0 >= 2) ? b2f(xr[base + (size_t)(t0 - 2) * D_]) : 0.f;
    float xm1 = (t0 >= 1) ? b2f(xr[base + (size_t)(t0 - 1) * D_]) : 0.f;

    float h[4];
    {
        const size_t o = ((size_t)(b * SCAN_C + chunk) * D_ + d) * N_ + ng * 4;
        const float4 h4 = *reinterpret_cast<const float4*>(&Hstart[o]);
        h[0] = h4.x; h[1] = h4.y; h[2] = h4.z; h[3] = h4.w;
    }

#pragma unroll
    for (int s = 0; s < SCAN_S; ++s) {
        const size_t idx = base + (size_t)(t0 + s) * D_;
        const float xc = b2f(xr[idx]);
        const float uv = silu_f(cw4.x * xm3 + cw4.y * xm2 + cw4.z * xm1 + cw4.w * xc);
        xm3 = xm2; xm2 = xm1; xm1 = xc;
        const float dtv = b2f(dt[idx]);
        float yp = 0.f;
#pragma unroll
        for (int j = 0; j < 4; ++j) {
            const float ex = fminf(dtv * a_v[j], 0.f);
            const float at = expf(ex);
            const float bt = (fabsf(a_v[j]) < 1e-8f) ? dtv : (at - 1.f) * inv_a[j];
            const float bp = pbuf[s * 32 + ng * 4 + j];
            const float cp = pbuf[s * 32 + 16 + ng * 4 + j];
            h[j] = at * h[j] + bt * bp * uv;
            yp += cp * h[j];
        }
        yp += __shfl_xor(yp, 1);
        yp += __shfl_xor(yp, 2);
        if (ng == 0) {
            const float zv = b2f(z[idx]);
            yg[idx] = f2b((yp + uv * Dpd) * silu_f(zv));
        }
    }
}

// ---------- launch ----------
extern "C" void kernel_launch(void* const* d_in, const int* in_sizes, int n_in,
                              void* d_out, int out_size, void* d_ws, size_t ws_size,
                              hipStream_t stream) {
    (void)in_sizes; (void)n_in; (void)out_size;
    const int* ids = (const int*)d_in[0];
    const int* tsteps = (const int*)d_in[1];
    const float* emb = (const float*)d_in[2];
    const float* tw1 = (const float*)d_in[3];
    const float* tb1 = (const float*)d_in[4];
    const float* tw2 = (const float*)d_in[5];
    const float* tb2 = (const float*)d_in[6];
    const float* ln1s = (const float*)d_in[7];
    const float* ln1b = (const float*)d_in[8];
    const float* wx = (const float*)d_in[9];
    const float* wz = (const float*)d_in[10];
    const float* wp = (const float*)d_in[11];
    const float* convw = (const float*)d_in[12];
    const float* dtw = (const float*)d_in[13];
    const float* dtb = (const float*)d_in[14];
    const float* alog = (const float*)d_in[15];
    const float* dp = (const float*)d_in[16];
    const float* wo = (const float*)d_in[17];
    const float* ln2s = (const float*)d_in[18];
    const float* ln2b = (const float*)d_in[19];
    const float* mw1 = (const float*)d_in[20];
    const float* mb1 = (const float*)d_in[21];
    const float* mw2 = (const float*)d_in[22];
    const float* mb2 = (const float*)d_in[23];
    const float* lnos = (const float*)d_in[24];
    const float* lnob = (const float*)d_in[25];
    const float* hw = (const float*)d_in[26];
    const float* hb = (const float*)d_in[27];
    float* outp = (float*)d_out;

    char* w = (char*)d_ws;
    size_t used = 0;
    auto alloc = [&](size_t bytes) {
        char* pp = w;
        size_t rb = (bytes + 255) & ~(size_t)255;
        w += rb;
        used += rb;
        return pp;
    };
    float* x = (float*)alloc((size_t)MROWS * D_ * 4);
    float* t0f = (float*)alloc((size_t)B_ * D_ * 4);
    float* t1f = (float*)alloc((size_t)B_ * MLP_ * 4);
    float* t2f = (float*)alloc((size_t)B_ * D_ * 4);
    u16* xnb = (u16*)alloc((size_t)MROWS * D_ * 2);
    u16* xres = (u16*)alloc((size_t)MROWS * D_ * 2);
    u16* zb = (u16*)alloc((size_t)MROWS * D_ * 2);
    float* pf = (float*)alloc((size_t)MROWS * 96 * 4);
    u16* dtb16 = (u16*)alloc((size_t)MROWS * D_ * 2);
    u16* ygb = (u16*)alloc((size_t)MROWS * D_ * 2);
    const bool cvt_head = (ws_size >= used + (size_t)V_ * D_ * 2 + 4096);
    u16* hwb = cvt_head ? (u16*)alloc((size_t)V_ * D_ * 2) : nullptr;
    const size_t lw_bytes = ((size_t)DEPTH_ * D_ * D_ * 3 + (size_t)DEPTH_ * 96 * D_ +
                             (size_t)DEPTH_ * D_ * R_ + (size_t)DEPTH_ * MLP_ * D_ * 2) * 2;
    const bool cvt_layer = cvt_head && (ws_size >= used + lw_bytes + ((size_t)1 << 20));
    u16 *wxb = nullptr, *wzb = nullptr, *wpb = nullptr, *dtwb = nullptr, *wob = nullptr,
        *mw1b = nullptr, *mw2b = nullptr;
    if (cvt_layer) {
        wxb = (u16*)alloc((size_t)DEPTH_ * D_ * D_ * 2);
        wzb = (u16*)alloc((size_t)DEPTH_ * D_ * D_ * 2);
        wpb = (u16*)alloc((size_t)DEPTH_ * 96 * D_ * 2);
        dtwb = (u16*)alloc((size_t)DEPTH_ * D_ * R_ * 2);
        wob = (u16*)alloc((size_t)DEPTH_ * D_ * D_ * 2);
        mw1b = (u16*)alloc((size_t)DEPTH_ * MLP_ * D_ * 2);
        mw2b = (u16*)alloc((size_t)DEPTH_ * MLP_ * D_ * 2);
    }
    u16* m1b = (u16*)outp;  // MLP hidden scratch in d_out (overwritten by head)
    float* Aprod = outp + (size_t)6 * 1024 * 1024;
    float* Hloc = outp + (size_t)8 * 1024 * 1024;
    float* Hstart = outp + (size_t)10 * 1024 * 1024;

    auto cvt = [&](const float* src, u16* dst, size_t n) {
        cvt_kernel<<<dim3((unsigned)((n / 8 + 255) / 256)), dim3(256), 0, stream>>>(src, dst,
                                                                                   (int)(n / 8));
    };
    if (cvt_head) cvt(hw, hwb, (size_t)V_ * D_);
    if (cvt_layer) {
        cvt(wx, wxb, (size_t)DEPTH_ * D_ * D_);
        cvt(wz, wzb, (size_t)DEPTH_ * D_ * D_);
        cvt(wp, wpb, (size_t)DEPTH_ * 96 * D_);
        cvt(dtw, dtwb, (size_t)DEPTH_ * D_ * R_);
        cvt(wo, wob, (size_t)DEPTH_ * D_ * D_);
        cvt(mw1, mw1b, (size_t)DEPTH_ * MLP_ * D_);
        cvt(mw2, mw2b, (size_t)DEPTH_ * MLP_ * D_);
    }
    temb0_kernel<<<dim3((B_ * D_ + 255) / 256), dim3(256), 0, stream>>>(tsteps, t0f);
    rowdot_kernel<1><<<dim3(B_ * MLP_ / 4), dim3(256), 0, stream>>>(t0f, tw1, tb1, t1f, MLP_, D_);
    rowdot_kernel<0><<<dim3(B_ * D_ / 4), dim3(256), 0, stream>>>(t1f, tw2, tb2, t2f, D_, MLP_);
    embed_kernel<<<dim3(MROWS * D_ / 8 / 256), dim3(256), 0, stream>>>(ids, emb, t2f, x);

    for (int i = 0; i < DEPTH_; ++i) {
        const float* cwi = convw + (size_t)i * D_ * 4;
        const float* dtbi = dtb + (size_t)i * D_;
        const float* ali = alog + (size_t)i * D_ * N_;
        const float* dpi = dp + (size_t)i * D_;
        const float* mb1i = mb1 + (size_t)i * MLP_;
        const float* mb2i = mb2 + (size_t)i * D_;

        ln_kernel<<<dim3(MROWS), dim3(256), 0, stream>>>(x, ln1s + i * D_, ln1b + i * D_, xnb);
        if (cvt_layer) {
            gemm_bt<32, 64, 0, 0, 1, u16, u16, u16><<<dim3(1024), dim3(256), 0, stream>>>(
                xnb, D_, wxb + (size_t)i * D_ * D_, wzb + (size_t)i * D_ * D_, nullptr,
                xres, zb, D_, D_, 32, 0);
            gemm_bt<32, 64, 0, 0, 1, u16, u16, float><<<dim3(64), dim3(256), 0, stream>>>(
                xnb, D_, wpb + (size_t)i * 96 * D_, nullptr, nullptr, pf, nullptr, 96, D_, 2, 0);
            gemm_bt<32, 64, 2, 0, 1, float, u16, u16><<<dim3(512), dim3(256), 0, stream>>>(
                pf, 96, dtwb + (size_t)i * D_ * R_, nullptr, dtbi, dtb16, nullptr, D_, R_, 16, 0);
        } else {
            gemm_bt<32, 64, 0, 0, 1, u16, float, u16><<<dim3(1024), dim3(256), 0, stream>>>(
                xnb, D_, wx + (size_t)i * D_ * D_, wz + (size_t)i * D_ * D_, nullptr,
                xres, zb, D_, D_, 32, 0);
            gemm_bt<32, 64, 0, 0, 1, u16, float, float><<<dim3(64), dim3(256), 0, stream>>>(
                xnb, D_, wp + (size_t)i * 96 * D_, nullptr, nullptr, pf, nullptr, 96, D_, 2, 0);
            gemm_bt<32, 64, 2, 0, 1, float, float, u16><<<dim3(512), dim3(256), 0, stream>>>(
                pf, 96, dtw + (size_t)i * D_ * R_, nullptr, dtbi, dtb16, nullptr, D_, R_, 16, 0);
        }
        scan_p1<<<dim3(B_ * (D_ / 64) * SCAN_C), dim3(256), 0, stream>>>(
            dtb16, pf, xres, cwi, ali, Aprod, Hloc);
        scan_p2<<<dim3(B_ * D_ * N_ / 256), dim3(256), 0, stream>>>(Aprod, Hloc, Hstart);
        scan_p3<<<dim3(B_ * (D_ / 64) * SCAN_C), dim3(256), 0, stream>>>(
            dtb16, pf, xres, cwi, zb, ali, dpi, Hstart, ygb);
        if (cvt_layer) {
            gemm_bt<32, 64, 0, 1, 1, u16, u16, float><<<dim3(512), dim3(256), 0, stream>>>(
                ygb, D_, wob + (size_t)i * D_ * D_, nullptr, nullptr, x, nullptr, D_, D_, 16, 0);
        } else {
            gemm_bt<32, 64, 0, 1, 1, u16, float, float><<<dim3(512), dim3(256), 0, stream>>>(
                ygb, D_, wo + (size_t)i * D_ * D_, nullptr, nullptr, x, nullptr, D_, D_, 16, 0);
        }
        ln_kernel<<<dim3(MROWS), dim3(256), 0, stream>>>(x, ln2s + i * D_, ln2b + i * D_, xnb);
        if (cvt_layer) {
            gemm_bt<32, 64, 1, 0, 1, u16, u16, u16><<<dim3(2048), dim3(256), 0, stream>>>(
                xnb, D_, mw1b + (size_t)i * MLP_ * D_, nullptr, mb1i, m1b, nullptr, MLP_, D_, 64, 0);
            gemm_bt<32, 64, 0, 1, 1, u16, u16, float><<<dim3(512), dim3(256), 0, stream>>>(
                m1b, MLP_, mw2b + (size_t)i * MLP_ * D_, nullptr, mb2i, x, nullptr, D_, MLP_, 16, 0);
        } else {
            gemm_bt<32, 64, 1, 0, 1, u16, float, u16><<<dim3(2048), dim3(256), 0, stream>>>(
                xnb, D_, mw1 + (size_t)i * MLP_ * D_, nullptr, mb1i, m1b, nullptr, MLP_, D_, 64, 0);
            gemm_bt<32, 64, 0, 1, 1, u16, float, float><<<dim3(512), dim3(256), 0, stream>>>(
                m1b, MLP_, mw2 + (size_t)i * MLP_ * D_, nullptr, mb2i, x, nullptr, D_, MLP_, 16, 0);
        }
    }

    ln_kernel<<<dim3(MROWS), dim3(256), 0, stream>>>(x, lnos, lnob, xnb);
    // head: r13 config via PIPEOK=0 / gsz=0 (single-buffered DMA, n-major, no supertile)
    // — 183 us measured in r18/r19. ONLY the template args of this call differ from the
    // round-17 build (975 us, layers in the fast 737-us cluster); everything else is
    // byte-identical to minimize codegen perturbation (rule #19).
    constexpr int HNT = (V_ + 127) / 128;  // 391
    if (cvt_head) {
        gemm_bt<128, 128, 0, 0, 0, u16, u16, float>
            <<<dim3(8 * HNT), dim3(256), 0, stream>>>(
                xnb, D_, hwb, (const u16*)nullptr, hb, outp, nullptr, V_, D_, HNT, 0);
    } else {
        gemm_bt<128, 128, 0, 0, 0, u16, float, float>
            <<<dim3(8 * HNT), dim3(256), 0, stream>>>(
                xnb, D_, hw, (const float*)nullptr, hb, outp, nullptr, V_, D_, HNT, 0);
    }
}

// Round 21
// 927.279 us; speedup vs baseline: 1.1505x; 1.0056x over previous
//
#include <hip/hip_runtime.h>

typedef unsigned short u16;
typedef __attribute__((ext_vector_type(8))) __bf16 bf16x8;
typedef __attribute__((ext_vector_type(4))) float floatx4;

#define B_ 2
#define L_ 512
#define D_ 1024
#define N_ 16
#define R_ 64
#define DEPTH_ 4
#define V_ 50000
#define MLP_ 4096
#define MROWS (B_ * L_)
#define SCAN_C 32
#define SCAN_S (L_ / SCAN_C)  // 16

// LDS XOR swizzle for 128-byte rows (BK=64 bf16). Involution: SWZ(SWZ(b)) == b.
#define SWZ(b) ((b) ^ ((((b) >> 7) & 7) << 4))

// ---------- helpers ----------
__device__ __forceinline__ float b2f(u16 u) {
    unsigned int i = ((unsigned int)u) << 16;
    return __builtin_bit_cast(float, i);
}
__device__ __forceinline__ u16 f2b(float f) {
    return __builtin_bit_cast(u16, (__bf16)f);
}
__device__ __forceinline__ uint2 f4_to_b4(float4 v) {
    u16 a = f2b(v.x), b = f2b(v.y), c = f2b(v.z), d = f2b(v.w);
    uint2 r;
    r.x = (unsigned int)a | ((unsigned int)b << 16);
    r.y = (unsigned int)c | ((unsigned int)d << 16);
    return r;
}
__device__ __forceinline__ void async16(const void* g, void* l) {
    __builtin_amdgcn_global_load_lds(
        (const __attribute__((address_space(1))) void*)g,
        (__attribute__((address_space(3))) void*)l, 16, 0, 0);
}
template <int Ncnt>
__device__ __forceinline__ void waitcnt_vm() {
    if constexpr (Ncnt == 0) asm volatile("s_waitcnt vmcnt(0)" ::: "memory");
    else if constexpr (Ncnt == 2) asm volatile("s_waitcnt vmcnt(2)" ::: "memory");
    else if constexpr (Ncnt == 3) asm volatile("s_waitcnt vmcnt(3)" ::: "memory");
    else if constexpr (Ncnt == 4) asm volatile("s_waitcnt vmcnt(4)" ::: "memory");
    else if constexpr (Ncnt == 6) asm volatile("s_waitcnt vmcnt(6)" ::: "memory");
    else if constexpr (Ncnt == 8) asm volatile("s_waitcnt vmcnt(8)" ::: "memory");
    else asm volatile("s_waitcnt vmcnt(0)" ::: "memory");
}
__device__ __forceinline__ float silu_f(float v) { return v / (1.f + expf(-v)); }
__device__ __forceinline__ float gelu_f(float v) {
    return 0.5f * v * (1.f + erff(v * 0.7071067811865476f));
}
__device__ __forceinline__ float softplus_f(float v) {
    return fmaxf(v, 0.f) + log1pf(expf(-fabsf(v)));
}

// ---------- f32 -> bf16 bulk convert ----------
__global__ __launch_bounds__(256) void cvt_kernel(const float* __restrict__ in,
                                                  u16* __restrict__ out, const int n8) {
    const int i = blockIdx.x * 256 + threadIdx.x;
    if (i >= n8) return;
    const float4 a = *reinterpret_cast<const float4*>(&in[(size_t)i * 8]);
    const float4 b = *reinterpret_cast<const float4*>(&in[(size_t)i * 8 + 4]);
    uint4 o;
    uint2 lo = f4_to_b4(a), hi = f4_to_b4(b);
    o.x = lo.x; o.y = lo.y; o.z = hi.x; o.w = hi.y;
    *reinterpret_cast<uint4*>(&out[(size_t)i * 8]) = o;
}

// ---------- MFMA GEMM: C[M,N] = act(A[M,K] @ W[N,K]^T + bias) ----------
// PIPEOK && both-u16: double-buffered DMA + counted vmcnt pipeline.
// Else: single-buffered (DMA for u16, reg-cvt for f32).
// gsz>0: supertile mapping (n-panel groups of gsz; all m-tiles inner) for L3 W reuse.
template <int BM, int BN, int ACT, int RES, int PIPEOK, typename AT, typename WT, typename OUT>
__global__ __launch_bounds__(256) void gemm_bt(
    const AT* __restrict__ A, const int lda,
    const WT* __restrict__ W, const WT* __restrict__ W2,
    const float* __restrict__ bias,
    OUT* __restrict__ out, OUT* __restrict__ out2,
    const int N, const int K, const int nt, const int gsz) {
    constexpr int BK = 64;
    constexpr int MI = BM / 32;
    constexpr int NI = BN / 32;
    constexpr int WM = BM / 2;
    constexpr bool PIPE = PIPEOK && (sizeof(AT) == 2) && (sizeof(WT) == 2);
    __shared__ alignas(16) u16 lA[(PIPE ? 2 : 1) * BM * BK];
    __shared__ alignas(16) u16 lW[(PIPE ? 2 : 1) * BN * BK];
    const int tid = threadIdx.x;
    const int lane = tid & 63, wv = tid >> 6;
    const int bid = blockIdx.x;

    int mI, nI;
    if (gsz > 0) {
        const int mtt = gridDim.x / nt;
        const int fullG = nt / gsz;
        const int fullBlocks = fullG * gsz * mtt;
        if (bid < fullBlocks) {
            const int per = gsz * mtt;
            const int g = bid / per, r = bid % per;
            mI = r / gsz;
            nI = g * gsz + r % gsz;
        } else {
            const int rem = nt - fullG * gsz;
            const int r = bid - fullBlocks;
            mI = r / rem;
            nI = fullG * gsz + r % rem;
        }
    } else {
        mI = bid / nt;
        nI = bid % nt;
    }
    const int m0 = mI * BM;
    int n0 = nI * BN;
    const WT* Wp = W;
    OUT* op = out;
    if (W2 != nullptr && n0 >= N) {
        Wp = W2;
        op = out2;
        n0 -= N;
    }
    const int wr = wv >> 1, wc = wv & 1;
    const int lr = lane & 15, kg = lane >> 4;

    floatx4 acc[MI][NI];
#pragma unroll
    for (int i = 0; i < MI; ++i)
#pragma unroll
        for (int j = 0; j < NI; ++j) {
            floatx4 z4 = {0.f, 0.f, 0.f, 0.f};
            acc[i][j] = z4;
        }

    const int T = K / BK;

    if constexpr (PIPE) {
        constexpr int NEWER = BM / 32 + BN / 32;
        auto issue = [&](int t) {
            const int buf = t & 1;
            const int kt = t * BK;
#pragma unroll
            for (int c = wv; c < BM / 8; c += 4) {
                const int dst = c * 1024 + lane * 16;
                const int lg = SWZ(dst);
                const int row = lg >> 7, colb = lg & 127;
                async16((const char*)A + ((size_t)(m0 + row) * lda + kt) * 2 + colb,
                        (char*)lA + buf * BM * 128 + c * 1024);
            }
#pragma unroll
            for (int c = wv; c < BN / 8; c += 4) {
                const int dst = c * 1024 + lane * 16;
                const int lg = SWZ(dst);
                const int row = lg >> 7, colb = lg & 127;
                int rn = n0 + row;
                rn = (rn < N) ? rn : (N - 1);
                async16((const char*)Wp + ((size_t)rn * K + kt) * 2 + colb,
                        (char*)lW + buf * BN * 128 + c * 1024);
            }
        };
        issue(0);
        for (int t = 0; t < T; ++t) {
            if (t + 1 < T) {
                issue(t + 1);
                waitcnt_vm<NEWER>();
            } else {
                waitcnt_vm<0>();
            }
            __builtin_amdgcn_s_barrier();
            __builtin_amdgcn_sched_barrier(0);
            const char* bA = (const char*)lA + (t & 1) * BM * 128;
            const char* bW = (const char*)lW + (t & 1) * BN * 128;
#pragma unroll
            for (int kk = 0; kk < 2; ++kk) {
                bf16x8 aF[MI], bF[NI];
#pragma unroll
                for (int mi = 0; mi < MI; ++mi)
                    aF[mi] = *reinterpret_cast<const bf16x8*>(
                        bA + SWZ((wr * WM + mi * 16 + lr) * 128 + kk * 64 + kg * 16));
#pragma unroll
                for (int ni = 0; ni < NI; ++ni)
                    bF[ni] = *reinterpret_cast<const bf16x8*>(
                        bW + SWZ((wc * (BN / 2) + ni * 16 + lr) * 128 + kk * 64 + kg * 16));
#pragma unroll
                for (int mi = 0; mi < MI; ++mi)
#pragma unroll
                    for (int ni = 0; ni < NI; ++ni)
                        acc[mi][ni] = __builtin_amdgcn_mfma_f32_16x16x32_bf16(
                            aF[mi], bF[ni], acc[mi][ni], 0, 0, 0);
            }
            __builtin_amdgcn_sched_barrier(0);
            if (t + 1 < T) __builtin_amdgcn_s_barrier();
        }
    } else {
        for (int t = 0; t < T; ++t) {
            const int kt = t * BK;
            if (t) __syncthreads();
            if constexpr (sizeof(AT) == 2) {
#pragma unroll
                for (int c = wv; c < BM / 8; c += 4) {
                    const int dst = c * 1024 + lane * 16;
                    const int lg = SWZ(dst);
                    const int row = lg >> 7, colb = lg & 127;
                    async16((const char*)A + ((size_t)(m0 + row) * lda + kt) * 2 + colb,
                            (char*)lA + c * 1024);
                }
            } else {
                constexpr int ACHF = (BM * BK) / 1024;
                float4 raF[ACHF];
#pragma unroll
                for (int i = 0; i < ACHF; ++i) {
                    const int idx = tid + i * 256;
                    const int row = idx >> 4, c4 = (idx & 15) * 4;
                    raF[i] = *reinterpret_cast<const float4*>(&A[(size_t)(m0 + row) * lda + kt + c4]);
                }
#pragma unroll
                for (int i = 0; i < ACHF; ++i) {
                    const int idx = tid + i * 256;
                    const int row = idx >> 4, c4 = (idx & 15) * 4;
                    *reinterpret_cast<uint2*>((char*)lA + SWZ(row * 128 + c4 * 2)) = f4_to_b4(raF[i]);
                }
            }
            if constexpr (sizeof(WT) == 2) {
#pragma unroll
                for (int c = wv; c < BN / 8; c += 4) {
                    const int dst = c * 1024 + lane * 16;
                    const int lg = SWZ(dst);
                    const int row = lg >> 7, colb = lg & 127;
                    int rn = n0 + row;
                    rn = (rn < N) ? rn : (N - 1);
                    async16((const char*)Wp + ((size_t)rn * K + kt) * 2 + colb,
                            (char*)lW + c * 1024);
                }
            } else {
                constexpr int WCHF = (BN * BK) / 1024;
                float4 rwF[WCHF];
#pragma unroll
                for (int i = 0; i < WCHF; ++i) {
                    const int idx = tid + i * 256;
                    const int row = idx >> 4, c4 = (idx & 15) * 4;
                    int rn = n0 + row;
                    rn = (rn < N) ? rn : (N - 1);
                    rwF[i] = *reinterpret_cast<const float4*>(&Wp[(size_t)rn * K + kt + c4]);
                }
#pragma unroll
                for (int i = 0; i < WCHF; ++i) {
                    const int idx = tid + i * 256;
                    const int row = idx >> 4, c4 = (idx & 15) * 4;
                    *reinterpret_cast<uint2*>((char*)lW + SWZ(row * 128 + c4 * 2)) = f4_to_b4(rwF[i]);
                }
            }
            __syncthreads();
#pragma unroll
            for (int kk = 0; kk < 2; ++kk) {
                bf16x8 aF[MI], bF[NI];
#pragma unroll
                for (int mi = 0; mi < MI; ++mi)
                    aF[mi] = *reinterpret_cast<const bf16x8*>(
                        (const char*)lA + SWZ((wr * WM + mi * 16 + lr) * 128 + kk * 64 + kg * 16));
#pragma unroll
                for (int ni = 0; ni < NI; ++ni)
                    bF[ni] = *reinterpret_cast<const bf16x8*>(
                        (const char*)lW + SWZ((wc * (BN / 2) + ni * 16 + lr) * 128 + kk * 64 + kg * 16));
#pragma unroll
                for (int mi = 0; mi < MI; ++mi)
#pragma unroll
                    for (int ni = 0; ni < NI; ++ni)
                        acc[mi][ni] = __builtin_amdgcn_mfma_f32_16x16x32_bf16(
                            aF[mi], bF[ni], acc[mi][ni], 0, 0, 0);
            }
        }
    }

    // epilogue: D layout col = lane&15, row = (lane>>4)*4 + r; mi->r->ni order.
#pragma unroll
    for (int mi = 0; mi < MI; ++mi) {
        const int rb = m0 + wr * WM + mi * 16 + kg * 4;
#pragma unroll
        for (int r = 0; r < 4; ++r) {
            const size_t rowoff = (size_t)(rb + r) * (size_t)N;
#pragma unroll
            for (int ni = 0; ni < NI; ++ni) {
                const int col = n0 + wc * (BN / 2) + ni * 16 + lr;
                if (col >= N) continue;
                float v = acc[mi][ni][r] + (bias ? bias[col] : 0.f);
                if constexpr (ACT == 1) v = gelu_f(v);
                if constexpr (ACT == 2) v = softplus_f(v);
                const size_t o = rowoff + (size_t)col;
                if constexpr (RES) {
                    op[o] += v;
                } else if constexpr (sizeof(OUT) == 2) {
                    op[o] = f2b(v);
                } else {
                    op[o] = v;
                }
            }
        }
    }
}

// ---------- timestep embedding base ----------
__global__ __launch_bounds__(256) void temb0_kernel(const int* __restrict__ ts,
                                                    float* __restrict__ temb0) {
    int i = blockIdx.x * 256 + threadIdx.x;
    if (i >= B_ * D_) return;
    int b = i >> 10, k = i & 1023;
    float t = (float)ts[b];
    int h = (k < 512) ? k : (k - 512);
    float f = expf((float)h * (-9.210340371976184f / 511.f));
    float e = t * f;
    temb0[i] = (k < 512) ? sinf(e) : cosf(e);
}

// ---------- small row-dot GEMM (M=B) ----------
template <int ACTV>
__global__ __launch_bounds__(256) void rowdot_kernel(const float* __restrict__ in,
                                                     const float* __restrict__ W,
                                                     const float* __restrict__ bias,
                                                     float* __restrict__ out,
                                                     const int Ncols, const int K) {
    const int g = (blockIdx.x * 256 + threadIdx.x) >> 6;
    const int lane = threadIdx.x & 63;
    if (g >= B_ * Ncols) return;
    const int b = g / Ncols, j = g % Ncols;
    const float* xr = in + (size_t)b * K;
    const float* wr = W + (size_t)j * K;
    float s = 0.f;
    for (int k = lane; k < K; k += 64) s += xr[k] * wr[k];
#pragma unroll
    for (int o = 32; o; o >>= 1) s += __shfl_xor(s, o);
    if (lane == 0) {
        float v = s + bias[j];
        if (ACTV == 1) v = silu_f(v);
        out[(size_t)b * Ncols + j] = v;
    }
}

// ---------- embedding + temb broadcast ----------
__global__ __launch_bounds__(256) void embed_kernel(const int* __restrict__ ids,
                                                    const float* __restrict__ emb,
                                                    const float* __restrict__ temb2,
                                                    float* __restrict__ x) {
    const int gid = blockIdx.x * 256 + threadIdx.x;
    const int d8 = gid & 127;
    const int row = gid >> 7;
    const int b = row >> 9;
    const int d0 = d8 * 8;
    const int id = ids[row];
    const float4 e0 = *reinterpret_cast<const float4*>(&emb[(size_t)id * D_ + d0]);
    const float4 e1 = *reinterpret_cast<const float4*>(&emb[(size_t)id * D_ + d0 + 4]);
    const float4 t0 = *reinterpret_cast<const float4*>(&temb2[b * D_ + d0]);
    const float4 t1 = *reinterpret_cast<const float4*>(&temb2[b * D_ + d0 + 4]);
    float4 o0, o1;
    o0.x = e0.x + t0.x; o0.y = e0.y + t0.y; o0.z = e0.z + t0.z; o0.w = e0.w + t0.w;
    o1.x = e1.x + t1.x; o1.y = e1.y + t1.y; o1.z = e1.z + t1.z; o1.w = e1.w + t1.w;
    *reinterpret_cast<float4*>(&x[(size_t)row * D_ + d0]) = o0;
    *reinterpret_cast<float4*>(&x[(size_t)row * D_ + d0 + 4]) = o1;
}

// ---------- LayerNorm (f32 in, bf16 out) ----------
__global__ __launch_bounds__(256) void ln_kernel(const float* __restrict__ x,
                                                 const float* __restrict__ s,
                                                 const float* __restrict__ bb,
                                                 u16* __restrict__ out) {
    __shared__ float red[4];
    const int row = blockIdx.x, tid = threadIdx.x;
    const float4 v = *reinterpret_cast<const float4*>(x + (size_t)row * D_ + tid * 4);
    float sm = v.x + v.y + v.z + v.w;
#pragma unroll
    for (int o = 1; o < 64; o <<= 1) sm += __shfl_xor(sm, o);
    if ((tid & 63) == 0) red[tid >> 6] = sm;
    __syncthreads();
    const float mean = (red[0] + red[1] + red[2] + red[3]) * (1.f / 1024.f);
    __syncthreads();
    const float dx = v.x - mean, dy = v.y - mean, dz = v.z - mean, dw = v.w - mean;
    float sq = dx * dx + dy * dy + dz * dz + dw * dw;
#pragma unroll
    for (int o = 1; o < 64; o <<= 1) sq += __shfl_xor(sq, o);
    if ((tid & 63) == 0) red[tid >> 6] = sq;
    __syncthreads();
    const float var = (red[0] + red[1] + red[2] + red[3]) * (1.f / 1024.f);
    const float rs = rsqrtf(var + 1e-5f);
    const int c = tid * 4;
    const float4 sv = *reinterpret_cast<const float4*>(&s[c]);
    const float4 bv = *reinterpret_cast<const float4*>(&bb[c]);
    float4 o;
    o.x = dx * rs * sv.x + bv.x;
    o.y = dy * rs * sv.y + bv.y;
    o.z = dz * rs * sv.z + bv.z;
    o.w = dw * rs * sv.w + bv.w;
    *reinterpret_cast<uint2*>(&out[(size_t)row * D_ + c]) = f4_to_b4(o);
}

// ---------- chunked parallel selective scan, conv fused (sliding window) ----------
__global__ __launch_bounds__(256) void scan_p1(const u16* __restrict__ dt,
                                               const float* __restrict__ p,
                                               const u16* __restrict__ xr,
                                               const float* __restrict__ cw,
                                               const float* __restrict__ alog,
                                               float* __restrict__ Aprod,
                                               float* __restrict__ Hloc) {
    const int tid = threadIdx.x;
    const int ng = tid & 3;
    const int dl = tid >> 2;
    int blk = blockIdx.x;
    const int chunk = blk % SCAN_C; blk /= SCAN_C;
    const int dg = blk % (D_ / 64);
    const int b = blk / (D_ / 64);
    const int d = dg * 64 + dl;

    float a_v[4], inv_a[4];
#pragma unroll
    for (int j = 0; j < 4; ++j) {
        float av = -expf(alog[d * N_ + ng * 4 + j]);
        a_v[j] = av;
        inv_a[j] = 1.f / (av + 1e-10f);
    }
    const float4 cw4 = *reinterpret_cast<const float4*>(&cw[d * 4]);

    __shared__ float pbuf[SCAN_S * 32];
    const int t0 = chunk * SCAN_S;
    if (tid < SCAN_S * 8) {
        const int s = tid >> 3, off = (tid & 7) * 4;
        *reinterpret_cast<float4*>(&pbuf[s * 32 + off]) =
            *reinterpret_cast<const float4*>(&p[((size_t)(b * L_ + t0 + s)) * 96 + 64 + off]);
    }
    __syncthreads();

    const size_t base = (size_t)b * L_ * D_ + d;
    float xm3 = (t0 >= 3) ? b2f(xr[base + (size_t)(t0 - 3) * D_]) : 0.f;
    float xm2 = (t0 >= 2) ? b2f(xr[base + (size_t)(t0 - 2) * D_]) : 0.f;
    float xm1 = (t0 >= 1) ? b2f(xr[base + (size_t)(t0 - 1) * D_]) : 0.f;

    float A[4] = {1.f, 1.f, 1.f, 1.f};
    float h[4] = {0.f, 0.f, 0.f, 0.f};
#pragma unroll
    for (int s = 0; s < SCAN_S; ++s) {
        const size_t idx = base + (size_t)(t0 + s) * D_;
        const float xc = b2f(xr[idx]);
        const float uv = silu_f(cw4.x * xm3 + cw4.y * xm2 + cw4.z * xm1 + cw4.w * xc);
        xm3 = xm2; xm2 = xm1; xm1 = xc;
        const float dtv = b2f(dt[idx]);
#pragma unroll
        for (int j = 0; j < 4; ++j) {
            const float ex = fminf(dtv * a_v[j], 0.f);
            const float at = expf(ex);
            const float bt = (fabsf(a_v[j]) < 1e-8f) ? dtv : (at - 1.f) * inv_a[j];
            const float bp = pbuf[s * 32 + ng * 4 + j];
            A[j] *= at;
            h[j] = at * h[j] + bt * bp * uv;
        }
    }
    const size_t o = ((size_t)(b * SCAN_C + chunk) * D_ + d) * N_ + ng * 4;
    float4 a4 = {A[0], A[1], A[2], A[3]};
    float4 h4 = {h[0], h[1], h[2], h[3]};
    *reinterpret_cast<float4*>(&Aprod[o]) = a4;
    *reinterpret_cast<float4*>(&Hloc[o]) = h4;
}

__global__ __launch_bounds__(256) void scan_p2(const float* __restrict__ Aprod,
                                               const float* __restrict__ Hloc,
                                               float* __restrict__ Hstart) {
    const int gid = blockIdx.x * 256 + threadIdx.x;
    if (gid >= B_ * D_ * N_) return;
    const int b = gid / (D_ * N_);
    const int rem = gid % (D_ * N_);
    float H = 0.f;
#pragma unroll 8
    for (int k = 0; k < SCAN_C; ++k) {
        const size_t o = (size_t)(b * SCAN_C + k) * (D_ * N_) + rem;
        Hstart[o] = H;
        H = Aprod[o] * H + Hloc[o];
    }
}

__global__ __launch_bounds__(256) void scan_p3(const u16* __restrict__ dt,
                                               const float* __restrict__ p,
                                               const u16* __restrict__ xr,
                                               const float* __restrict__ cw,
                                               const u16* __restrict__ z,
                                               const float* __restrict__ alog,
                                               const float* __restrict__ Dp,
                                               const float* __restrict__ Hstart,
                                               u16* __restrict__ yg) {
    const int tid = threadIdx.x;
    const int ng = tid & 3;
    const int dl = tid >> 2;
    int blk = blockIdx.x;
    const int chunk = blk % SCAN_C; blk /= SCAN_C;
    const int dg = blk % (D_ / 64);
    const int b = blk / (D_ / 64);
    const int d = dg * 64 + dl;

    float a_v[4], inv_a[4];
#pragma unroll
    for (int j = 0; j < 4; ++j) {
        float av = -expf(alog[d * N_ + ng * 4 + j]);
        a_v[j] = av;
        inv_a[j] = 1.f / (av + 1e-10f);
    }
    const float Dpd = Dp[d];
    const float4 cw4 = *reinterpret_cast<const float4*>(&cw[d * 4]);

    __shared__ float pbuf[SCAN_S * 32];
    const int t0 = chunk * SCAN_S;
    if (tid < SCAN_S * 8) {
        const int s = tid >> 3, off = (tid & 7) * 4;
        *reinterpret_cast<float4*>(&pbuf[s * 32 + off]) =
            *reinterpret_cast<const float4*>(&p[((size_t)(b * L_ + t0 + s)) * 96 + 64 + off]);
    }
    __syncthreads();

    const size_t base = (size_t)b * L_ * D_ + d;
    float xm3 = (t0 >= 3) ? b2f(xr[base + (size_t)(t0 - 3) * D_]) : 0.f;
    float xm2 = (t0 >= 2) ? b2f(xr[base + (size_t)(t0 - 2) * D_]) : 0.f;
    float xm1 = (t0 >= 1) ? b2f(xr[base + (size_t)(t0 - 1) * D_]) : 0.f;

    float h[4];
    {
        const size_t o = ((size_t)(b * SCAN_C + chunk) * D_ + d) * N_ + ng * 4;
        const float4 h4 = *reinterpret_cast<const float4*>(&Hstart[o]);
        h[0] = h4.x; h[1] = h4.y; h[2] = h4.z; h[3] = h4.w;
    }

#pragma unroll
    for (int s = 0; s < SCAN_S; ++s) {
        const size_t idx = base + (size_t)(t0 + s) * D_;
        const float xc = b2f(xr[idx]);
        const float uv = silu_f(cw4.x * xm3 + cw4.y * xm2 + cw4.z * xm1 + cw4.w * xc);
        xm3 = xm2; xm2 = xm1; xm1 = xc;
        const float dtv = b2f(dt[idx]);
        float yp = 0.f;
#pragma unroll
        for (int j = 0; j < 4; ++j) {
            const float ex = fminf(dtv * a_v[j], 0.f);
            const float at = expf(ex);
            const float bt = (fabsf(a_v[j]) < 1e-8f) ? dtv : (at - 1.f) * inv_a[j];
            const float bp = pbuf[s * 32 + ng * 4 + j];
            const float cp = pbuf[s * 32 + 16 + ng * 4 + j];
            h[j] = at * h[j] + bt * bp * uv;
            yp += cp * h[j];
        }
        yp += __shfl_xor(yp, 1);
        yp += __shfl_xor(yp, 2);
        if (ng == 0) {
            const float zv = b2f(z[idx]);
            yg[idx] = f2b((yp + uv * Dpd) * silu_f(zv));
        }
    }
}

// ---------- launch ----------
extern "C" void kernel_launch(void* const* d_in, const int* in_sizes, int n_in,
                              void* d_out, int out_size, void* d_ws, size_t ws_size,
                              hipStream_t stream) {
    (void)in_sizes; (void)n_in; (void)out_size;
    const int* ids = (const int*)d_in[0];
    const int* tsteps = (const int*)d_in[1];
    const float* emb = (const float*)d_in[2];
    const float* tw1 = (const float*)d_in[3];
    const float* tb1 = (const float*)d_in[4];
    const float* tw2 = (const float*)d_in[5];
    const float* tb2 = (const float*)d_in[6];
    const float* ln1s = (const float*)d_in[7];
    const float* ln1b = (const float*)d_in[8];
    const float* wx = (const float*)d_in[9];
    const float* wz = (const float*)d_in[10];
    const float* wp = (const float*)d_in[11];
    const float* convw = (const float*)d_in[12];
    const float* dtw = (const float*)d_in[13];
    const float* dtb = (const float*)d_in[14];
    const float* alog = (const float*)d_in[15];
    const float* dp = (const float*)d_in[16];
    const float* wo = (const float*)d_in[17];
    const float* ln2s = (const float*)d_in[18];
    const float* ln2b = (const float*)d_in[19];
    const float* mw1 = (const float*)d_in[20];
    const float* mb1 = (const float*)d_in[21];
    const float* mw2 = (const float*)d_in[22];
    const float* mb2 = (const float*)d_in[23];
    const float* lnos = (const float*)d_in[24];
    const float* lnob = (const float*)d_in[25];
    const float* hw = (const float*)d_in[26];
    const float* hb = (const float*)d_in[27];
    float* outp = (float*)d_out;

    char* w = (char*)d_ws;
    size_t used = 0;
    auto alloc = [&](size_t bytes) {
        char* pp = w;
        size_t rb = (bytes + 255) & ~(size_t)255;
        w += rb;
        used += rb;
        return pp;
    };
    float* x = (float*)alloc((size_t)MROWS * D_ * 4);
    float* t0f = (float*)alloc((size_t)B_ * D_ * 4);
    float* t1f = (float*)alloc((size_t)B_ * MLP_ * 4);
    float* t2f = (float*)alloc((size_t)B_ * D_ * 4);
    u16* xnb = (u16*)alloc((size_t)MROWS * D_ * 2);
    u16* xres = (u16*)alloc((size_t)MROWS * D_ * 2);
    u16* zb = (u16*)alloc((size_t)MROWS * D_ * 2);
    float* pf = (float*)alloc((size_t)MROWS * 96 * 4);
    u16* dtb16 = (u16*)alloc((size_t)MROWS * D_ * 2);
    u16* ygb = (u16*)alloc((size_t)MROWS * D_ * 2);
    const bool cvt_head = (ws_size >= used + (size_t)V_ * D_ * 2 + 4096);
    u16* hwb = cvt_head ? (u16*)alloc((size_t)V_ * D_ * 2) : nullptr;
    const size_t lw_bytes = ((size_t)DEPTH_ * D_ * D_ * 3 + (size_t)DEPTH_ * 96 * D_ +
                             (size_t)DEPTH_ * D_ * R_ + (size_t)DEPTH_ * MLP_ * D_ * 2) * 2;
    const bool cvt_layer = cvt_head && (ws_size >= used + lw_bytes + ((size_t)1 << 20));
    u16 *wxb = nullptr, *wzb = nullptr, *wpb = nullptr, *dtwb = nullptr, *wob = nullptr,
        *mw1b = nullptr, *mw2b = nullptr;
    if (cvt_layer) {
        wxb = (u16*)alloc((size_t)DEPTH_ * D_ * D_ * 2);
        wzb = (u16*)alloc((size_t)DEPTH_ * D_ * D_ * 2);
        wpb = (u16*)alloc((size_t)DEPTH_ * 96 * D_ * 2);
        dtwb = (u16*)alloc((size_t)DEPTH_ * D_ * R_ * 2);
        wob = (u16*)alloc((size_t)DEPTH_ * D_ * D_ * 2);
        mw1b = (u16*)alloc((size_t)DEPTH_ * MLP_ * D_ * 2);
        mw2b = (u16*)alloc((size_t)DEPTH_ * MLP_ * D_ * 2);
    }
    u16* m1b = (u16*)outp;  // MLP hidden scratch in d_out (overwritten by head)
    float* Aprod = outp + (size_t)6 * 1024 * 1024;
    float* Hloc = outp + (size_t)8 * 1024 * 1024;
    float* Hstart = outp + (size_t)10 * 1024 * 1024;

    auto cvt = [&](const float* src, u16* dst, size_t n) {
        cvt_kernel<<<dim3((unsigned)((n / 8 + 255) / 256)), dim3(256), 0, stream>>>(src, dst,
                                                                                   (int)(n / 8));
    };
    if (cvt_head) cvt(hw, hwb, (size_t)V_ * D_);
    if (cvt_layer) {
        cvt(wx, wxb, (size_t)DEPTH_ * D_ * D_);
        cvt(wz, wzb, (size_t)DEPTH_ * D_ * D_);
        cvt(wp, wpb, (size_t)DEPTH_ * 96 * D_);
        cvt(dtw, dtwb, (size_t)DEPTH_ * D_ * R_);
        cvt(wo, wob, (size_t)DEPTH_ * D_ * D_);
        cvt(mw1, mw1b, (size_t)DEPTH_ * MLP_ * D_);
        cvt(mw2, mw2b, (size_t)DEPTH_ * MLP_ * D_);
    }
    temb0_kernel<<<dim3((B_ * D_ + 255) / 256), dim3(256), 0, stream>>>(tsteps, t0f);
    rowdot_kernel<1><<<dim3(B_ * MLP_ / 4), dim3(256), 0, stream>>>(t0f, tw1, tb1, t1f, MLP_, D_);
    rowdot_kernel<0><<<dim3(B_ * D_ / 4), dim3(256), 0, stream>>>(t1f, tw2, tb2, t2f, D_, MLP_);
    embed_kernel<<<dim3(MROWS * D_ / 8 / 256), dim3(256), 0, stream>>>(ids, emb, t2f, x);

    for (int i = 0; i < DEPTH_; ++i) {
        const float* cwi = convw + (size_t)i * D_ * 4;
        const float* dtbi = dtb + (size_t)i * D_;
        const float* ali = alog + (size_t)i * D_ * N_;
        const float* dpi = dp + (size_t)i * D_;
        const float* mb1i = mb1 + (size_t)i * MLP_;
        const float* mb2i = mb2 + (size_t)i * D_;

        ln_kernel<<<dim3(MROWS), dim3(256), 0, stream>>>(x, ln1s + i * D_, ln1b + i * D_, xnb);
        if (cvt_layer) {
            gemm_bt<32, 64, 0, 0, 1, u16, u16, u16><<<dim3(1024), dim3(256), 0, stream>>>(
                xnb, D_, wxb + (size_t)i * D_ * D_, wzb + (size_t)i * D_ * D_, nullptr,
                xres, zb, D_, D_, 32, 0);
            gemm_bt<32, 64, 0, 0, 1, u16, u16, float><<<dim3(64), dim3(256), 0, stream>>>(
                xnb, D_, wpb + (size_t)i * 96 * D_, nullptr, nullptr, pf, nullptr, 96, D_, 2, 0);
            gemm_bt<32, 64, 2, 0, 1, float, u16, u16><<<dim3(512), dim3(256), 0, stream>>>(
                pf, 96, dtwb + (size_t)i * D_ * R_, nullptr, dtbi, dtb16, nullptr, D_, R_, 16, 0);
        } else {
            gemm_bt<32, 64, 0, 0, 1, u16, float, u16><<<dim3(1024), dim3(256), 0, stream>>>(
                xnb, D_, wx + (size_t)i * D_ * D_, wz + (size_t)i * D_ * D_, nullptr,
                xres, zb, D_, D_, 32, 0);
            gemm_bt<32, 64, 0, 0, 1, u16, float, float><<<dim3(64), dim3(256), 0, stream>>>(
                xnb, D_, wp + (size_t)i * 96 * D_, nullptr, nullptr, pf, nullptr, 96, D_, 2, 0);
            gemm_bt<32, 64, 2, 0, 1, float, float, u16><<<dim3(512), dim3(256), 0, stream>>>(
                pf, 96, dtw + (size_t)i * D_ * R_, nullptr, dtbi, dtb16, nullptr, D_, R_, 16, 0);
        }
        scan_p1<<<dim3(B_ * (D_ / 64) * SCAN_C), dim3(256), 0, stream>>>(
            dtb16, pf, xres, cwi, ali, Aprod, Hloc);
        scan_p2<<<dim3(B_ * D_ * N_ / 256), dim3(256), 0, stream>>>(Aprod, Hloc, Hstart);
        scan_p3<<<dim3(B_ * (D_ / 64) * SCAN_C), dim3(256), 0, stream>>>(
            dtb16, pf, xres, cwi, zb, ali, dpi, Hstart, ygb);
        if (cvt_layer) {
            gemm_bt<32, 64, 0, 1, 1, u16, u16, float><<<dim3(512), dim3(256), 0, stream>>>(
                ygb, D_, wob + (size_t)i * D_ * D_, nullptr, nullptr, x, nullptr, D_, D_, 16, 0);
        } else {
            gemm_bt<32, 64, 0, 1, 1, u16, float, float><<<dim3(512), dim3(256), 0, stream>>>(
                ygb, D_, wo + (size_t)i * D_ * D_, nullptr, nullptr, x, nullptr, D_, D_, 16, 0);
        }
        ln_kernel<<<dim3(MROWS), dim3(256), 0, stream>>>(x, ln2s + i * D_, ln2b + i * D_, xnb);
        if (cvt_layer) {
            gemm_bt<32, 64, 1, 0, 1, u16, u16, u16><<<dim3(2048), dim3(256), 0, stream>>>(
                xnb, D_, mw1b + (size_t)i * MLP_ * D_, nullptr, mb1i, m1b, nullptr, MLP_, D_, 64, 0);
            gemm_bt<32, 64, 0, 1, 1, u16, u16, float><<<dim3(512), dim3(256), 0, stream>>>(
                m1b, MLP_, mw2b + (size_t)i * MLP_ * D_, nullptr, mb2i, x, nullptr, D_, MLP_, 16, 0);
        } else {
            gemm_bt<32, 64, 1, 0, 1, u16, float, u16><<<dim3(2048), dim3(256), 0, stream>>>(
                xnb, D_, mw1 + (size_t)i * MLP_ * D_, nullptr, mb1i, m1b, nullptr, MLP_, D_, 64, 0);
            gemm_bt<32, 64, 0, 1, 1, u16, float, float><<<dim3(512), dim3(256), 0, stream>>>(
                m1b, MLP_, mw2 + (size_t)i * MLP_ * D_, nullptr, mb2i, x, nullptr, D_, MLP_, 16, 0);
        }
    }

    ln_kernel<<<dim3(MROWS), dim3(256), 0, stream>>>(x, lnos, lnob, xnb);
    // head: BM=256/BN=64 single-buffered DMA, n-major. Halves W logical re-reads
    // (8 -> 4 m-bands; r20 head was ~BW-bound at 614 MB / 3.4 TB/s). Only this
    // instantiation's args differ from the r20 build (rule #19 minimal-diff).
    constexpr int HNT = (V_ + 63) / 64;  // 782
    if (cvt_head) {
        gemm_bt<256, 64, 0, 0, 0, u16, u16, float>
            <<<dim3(4 * HNT), dim3(256), 0, stream>>>(
                xnb, D_, hwb, (const u16*)nullptr, hb, outp, nullptr, V_, D_, HNT, 0);
    } else {
        gemm_bt<256, 64, 0, 0, 0, u16, float, float>
            <<<dim3(4 * HNT), dim3(256), 0, stream>>>(
                xnb, D_, hw, (const float*)nullptr, hb, outp, nullptr, V_, D_, HNT, 0);
    }
}